// Round 13
// baseline (878.801 us; speedup 1.0000x reference)
//
#include <hip/hip_runtime.h>
#include <hip/hip_cooperative_groups.h>
#include <hip/hip_bf16.h>
#include <math.h>

namespace cg = cooperative_groups;

#define NN 50000
#define EE 800000
#define HH 128
#define FF 128
#define GG 50
#define LL 6
#define H2D 64
#define OUT_DIM 12
#define NK 4096          // nearest-neighbor table intervals; knots 0..NK (4097)
#define NBLK 782         // ceil(NN/64)
#define SB 196           // scan blocks: ceil(NN/256)
#define NBUK 196         // scatter buckets: 256 nodes each
#define NB 392           // setup kernel blocks (cooperative)

typedef __bf16 bf16;
typedef __attribute__((ext_vector_type(8))) __bf16 bf16x8;
typedef __attribute__((ext_vector_type(4))) __bf16 bf16x4;
typedef __attribute__((ext_vector_type(4))) float f32x4;
typedef __attribute__((ext_vector_type(4))) unsigned u32x4;

#define DEV __device__ __forceinline__

// fast shifted-softplus: hw v_exp/v_log, err ~1e-6 << bf16 rounding
DEV float sspf(float x) {
    return fmaxf(x, 0.f) + __logf(1.f + __expf(-fabsf(x))) - 0.69314718055994531f;
}

DEV f32x4 mfma16(bf16x8 a, bf16x8 b, f32x4 c) {
    return __builtin_amdgcn_mfma_f32_16x16x32_bf16(a, b, c, 0, 0, 0);
}

DEV float blo(unsigned u) { return __uint_as_float(u << 16); }
DEV float bhi(unsigned u) { return __uint_as_float(u & 0xffff0000u); }

// -------- cooperative setup: prep+table+sort+xf0 in one launch ---------------
struct SetupArgs {
    const float *conv1_w, *conv2_w, *int_lin_w, *mlp_w1, *mlp_w2, *lin1_w, *lin2_w;
    bf16 *c1t, *c2t, *ilt, *w1t, *w2t, *l1t, *l2t;
    const float *mlp_b1, *mlp_b2;
    const int* edge_index; const float* edge_attr;
    int* hist; int* bsum; int* rs; int* bcur;
    int2* tmp8; int* es;
    const int* x_atoms; const float* emb;
    bf16* tab; bf16* hb; bf16* xf;
};

DEV void prep_job(const SetupArgs& a, int j, int tid) {
    const float* src = nullptr; bf16* dst = nullptr; int R = 0, C = 0, K = 0;
    if (j < 30) {
        int l = j / 5, m = j % 5;
        switch (m) {
            case 0: src = a.conv1_w + l * HH * FF;   dst = a.c1t + l * FF * HH;  R = HH; C = FF; K = HH; break;
            case 1: src = a.conv2_w + l * FF * HH;   dst = a.c2t + l * HH * FF;  R = FF; C = HH; K = FF; break;
            case 2: src = a.int_lin_w + l * HH * HH; dst = a.ilt + l * HH * HH;  R = HH; C = HH; K = HH; break;
            case 3: src = a.mlp_w1 + l * GG * FF;    dst = a.w1t + l * FF * 64;  R = GG; C = FF; K = 64; break;
            case 4: src = a.mlp_w2 + l * FF * FF;    dst = a.w2t + l * FF * FF;  R = FF; C = FF; K = FF; break;
        }
    } else if (j == 30) { src = a.lin1_w; dst = a.l1t; R = HH;  C = H2D; K = HH; }
    else                { src = a.lin2_w; dst = a.l2t; R = H2D; C = H2D; K = H2D; }
    int total = C * K;
    for (int idx = tid; idx < total; idx += 256) {
        int c = idx / K, r = idx - c * K;
        dst[idx] = (r < R) ? (bf16)src[r * C + c] : (bf16)0.f;
    }
}

DEV void table_job(const SetupArgs& a, int job, char* smem, int tid) {
    bf16* sW1 = (bf16*)smem;               // [128][72]
    bf16* sW2 = (bf16*)(smem + 18432);     // [128][136]
    bf16* sT1 = (bf16*)(smem + 53248);     // [64][136]
    int l = job / 65, rb = job % 65;
    const bf16* W1 = a.w1t + (size_t)l * 128 * 64;
    const bf16* W2 = a.w2t + (size_t)l * 128 * 128;
    for (int idx = tid * 8; idx < 128 * 64; idx += 2048) {
        int n = idx >> 6, k = idx & 63;
        *(bf16x8*)&sW1[n * 72 + k] = *(const bf16x8*)(W1 + idx);
    }
    for (int idx = tid * 8; idx < 128 * 128; idx += 2048) {
        int n = idx >> 7, k = idx & 127;
        *(bf16x8*)&sW2[n * 136 + k] = *(const bf16x8*)(W2 + idx);
    }
    int w = tid >> 6, lane = tid & 63, ln = lane & 15, kg = lane >> 4;
    int rowt = rb * 64 + w * 16;
    float d1 = (float)min(rowt + ln, NK) * (10.f / NK);
    const float step = 10.f / 49.f;
    const float coeff = -0.5f / (step * step);
    __syncthreads();
    f32x4 acc[8] = {};
#pragma unroll
    for (int k0 = 0; k0 < 64; k0 += 32) {
        bf16x8 av;
#pragma unroll
        for (int jj = 0; jj < 8; jj++) {
            int g = k0 + kg * 8 + jj;
            float diff = d1 - g * step;
            float v = (g < GG) ? __expf(coeff * diff * diff) : 0.f;
            av[jj] = (bf16)v;
        }
#pragma unroll
        for (int t = 0; t < 8; t++) {
            bf16x8 b = *(const bf16x8*)&sW1[(t * 16 + ln) * 72 + k0 + kg * 8];
            acc[t] = mfma16(av, b, acc[t]);
        }
    }
    const float* b1 = a.mlp_b1 + l * FF;
#pragma unroll
    for (int t = 0; t < 8; t++) {
        int colt = t * 16 + ln;
        float bb = b1[colt];
#pragma unroll
        for (int r = 0; r < 4; r++)
            sT1[(w * 16 + kg * 4 + r) * 136 + colt] = (bf16)sspf(acc[t][r] + bb);
    }
    __syncthreads();
    f32x4 acc2[8] = {};
#pragma unroll
    for (int k0 = 0; k0 < 128; k0 += 32) {
        bf16x8 av = *(const bf16x8*)&sT1[(w * 16 + ln) * 136 + k0 + kg * 8];
#pragma unroll
        for (int t = 0; t < 8; t++) {
            bf16x8 b = *(const bf16x8*)&sW2[(t * 16 + ln) * 136 + k0 + kg * 8];
            acc2[t] = mfma16(av, b, acc2[t]);
        }
    }
    const float* b2 = a.mlp_b2 + l * FF;
    float Cw[4]; int rrow[4];
#pragma unroll
    for (int r = 0; r < 4; r++) {
        int rr = rowt + kg * 4 + r;
        rrow[r] = rr;
        float dd = (float)min(rr, NK) * (10.f / NK);
        Cw[r] = 0.5f * (cosf(dd * 0.31415926535897932f) + 1.f);
    }
#pragma unroll
    for (int t = 0; t < 8; t++) {
        int colt = t * 16 + ln;
        float bb = b2[colt];
#pragma unroll
        for (int r = 0; r < 4; r++) {
            if (rrow[r] <= NK)
                a.tab[((size_t)l * (NK + 1) + rrow[r]) * FF + colt] = (bf16)((acc2[t][r] + bb) * Cw[r]);
        }
    }
}

DEV void xf0_job(const SetupArgs& a, int job, char* smem, int tid) {
    bf16* sB = (bf16*)smem;                // [128][136]
    for (int idx = tid * 8; idx < 128 * 128; idx += 2048) {
        int n = idx >> 7, k = idx & 127;
        *(bf16x8*)&sB[n * 136 + k] = *(const bf16x8*)(a.c1t + idx);
    }
    int w = tid >> 6, lane = tid & 63, ln = lane & 15, kg = lane >> 4;
    int rowt = job * 64 + w * 16;
    int nrow = rowt + ln;
    int arow = min(nrow, NN - 1);
    bool rowok = nrow < NN;
    int atom = a.x_atoms[arow];
    __syncthreads();
    f32x4 acc[8] = {};
#pragma unroll
    for (int k0 = 0; k0 < 128; k0 += 32) {
        const float* ep = a.emb + (size_t)atom * HH + k0 + kg * 8;
        f32x4 u0 = *(const f32x4*)ep;
        f32x4 u1 = *(const f32x4*)(ep + 4);
        bf16x8 av;
#pragma unroll
        for (int q = 0; q < 4; q++) { av[q] = (bf16)u0[q]; av[q + 4] = (bf16)u1[q]; }
        if (rowok) *(bf16x8*)(a.hb + (size_t)nrow * HH + k0 + kg * 8) = av;
#pragma unroll
        for (int t = 0; t < 8; t++) {
            bf16x8 b = *(const bf16x8*)&sB[(t * 16 + ln) * 136 + k0 + kg * 8];
            acc[t] = mfma16(av, b, acc[t]);
        }
    }
#pragma unroll
    for (int t = 0; t < 8; t++) {
        int colt = t * 16 + ln;
#pragma unroll
        for (int r = 0; r < 4; r++) {
            int orow = rowt + kg * 4 + r;
            if (orow < NN) a.xf[orow * FF + colt] = (bf16)acc[t][r];
        }
    }
}

__global__ __launch_bounds__(256) void setup_kernel(SetupArgs a) {
    cg::grid_group grid = cg::this_grid();
    __shared__ __align__(16) char smem[70656];
    __shared__ int aux[768];
    int tid = threadIdx.x, bid = blockIdx.x;
    int gtid = bid * 256 + tid;
    const int gsz = NB * 256;

    // P0: zero hist + weight transposes
    for (int i = gtid; i < NN; i += gsz) a.hist[i] = 0;
    if (bid < 32) prep_job(a, bid, tid);
    grid.sync();

    // P1: histogram of dst
    for (int e = gtid; e < EE; e += gsz) atomicAdd(&a.hist[a.edge_index[EE + e]], 1);
    grid.sync();

    // P2: scanA (blocks<196) + filter table build (blocks<390)
    if (bid < SB) {
        int* red = aux;
        int i = bid * 256 + tid;
        int v = (i < NN) ? a.hist[i] : 0;
        red[tid] = v;
        __syncthreads();
        for (int off = 128; off > 0; off >>= 1) {
            if (tid < off) red[tid] += red[tid + off];
            __syncthreads();
        }
        if (tid == 0) a.bsum[bid] = red[0];
        __syncthreads();
    }
    if (bid < 390) table_job(a, bid, smem, tid);
    grid.sync();

    // P3: scanB (block 0) + layer-0 xf (all blocks, grid-stride)
    if (bid == 0) {
        int* buf = aux;
        int v = (tid < SB) ? a.bsum[tid] : 0;
        buf[tid] = v;
        __syncthreads();
        for (int off = 1; off < 256; off <<= 1) {
            int y = (tid >= off) ? buf[tid - off] : 0;
            __syncthreads();
            buf[tid] += y;
            __syncthreads();
        }
        if (tid < SB) a.bsum[tid] = buf[tid] - v;   // exclusive
    }
    for (int job = bid; job < NBLK; job += NB) {
        __syncthreads();
        xf0_job(a, job, smem, tid);
    }
    grid.sync();

    // P4: scanC -> rs + bucket bases
    if (bid < SB) {
        int* buf = aux;
        int i = bid * 256 + tid;
        int v = (i < NN) ? a.hist[i] : 0;
        buf[tid] = v;
        __syncthreads();
        for (int off = 1; off < 256; off <<= 1) {
            int y = (tid >= off) ? buf[tid - off] : 0;
            __syncthreads();
            buf[tid] += y;
            __syncthreads();
        }
        if (i < NN) {
            int ex = buf[tid] - v + a.bsum[bid];
            a.rs[i] = ex;
            if (tid == 0) a.bcur[i >> 8] = ex;
        }
    }
    grid.sync();

    // P5: scat1 — bucket-grouped tmp (2048 edges/block)
    {
        int* cnt = aux; int* res = aux + 196;
        if (tid < NBUK) cnt[tid] = 0;
        __syncthreads();
        int e0 = bid * 2048;
        int pv[8], dd[8], bk[8];
#pragma unroll
        for (int i = 0; i < 8; i++) {
            int e = e0 + i * 256 + tid;
            if (e < EE) {
                int d = a.edge_index[EE + e];
                int k = (int)(a.edge_attr[e] * ((float)NK / 10.f) + 0.5f);
                k = min(k, NK);
                pv[i] = k | (a.edge_index[e] << 13);
                dd[i] = d;
                bk[i] = d >> 8;
                atomicAdd(&cnt[bk[i]], 1);
            } else bk[i] = -1;
        }
        __syncthreads();
        if (tid < NBUK) {
            int c = cnt[tid];
            res[tid] = (c > 0) ? atomicAdd(&a.bcur[tid], c) : 0;
            cnt[tid] = 0;
        }
        __syncthreads();
#pragma unroll
        for (int i = 0; i < 8; i++) {
            if (bk[i] >= 0) {
                int rank = atomicAdd(&cnt[bk[i]], 1);
                int2 v; v.x = pv[i]; v.y = dd[i];
                a.tmp8[res[bk[i]] + rank] = v;
            }
        }
    }
    grid.sync();

    // P6: scat2 — final dst-sorted es (dense window per bucket)
    if (bid < NBUK) {
        int* off_ = aux; int* loc = aux + 256;
        int nb0 = bid * 256;
        int nnb = min(256, NN - nb0);
        int base = a.rs[nb0];
        int end = (nb0 + 256 < NN) ? a.rs[nb0 + 256] : EE;
        loc[tid] = 0;
        if (tid < nnb) off_[tid] = a.rs[nb0 + tid] - base;
        __syncthreads();
        for (int e = base + tid; e < end; e += 256) {
            int2 v = a.tmp8[e];
            int nl = v.y - nb0;
            int rank = atomicAdd(&loc[nl], 1);
            a.es[base + off_[nl] + rank] = v.x;
        }
    }
}

// -------- edge kernel: CSR, one wave/node, nearest-knot, 4 edges/iter --------
__global__ __launch_bounds__(256) void edge_kernel(const int* __restrict__ es,
                                                   const int* __restrict__ rs,
                                                   const int* __restrict__ hist,
                                                   const bf16* __restrict__ xf,
                                                   const bf16* __restrict__ tab,
                                                   bf16* __restrict__ aggb) {
    int tid = threadIdx.x;
    int w = tid >> 6, lane = tid & 63;
    int q = lane >> 4, cl = lane & 15;      // quarter q handles edge 4j+q; lane covers ch [8cl,8cl+8)
    int n = blockIdx.x * 4 + w;
    int start = rs[n], deg = hist[n];
    float a0 = 0.f, a1 = 0.f, a2 = 0.f, a3 = 0.f;
    float a4 = 0.f, a5 = 0.f, a6 = 0.f, a7 = 0.f;
    for (int base = 0; base < deg; base += 64) {
        int cnt = min(deg - base, 64);
        int pv = (lane < cnt) ? es[start + base + lane] : 0;
        int iters = (cnt + 3) >> 2;
#pragma unroll 4
        for (int j = 0; j < iters; j++) {
            int jj = 4 * j + q;
            bool valid = jj < cnt;
            int v = __shfl(pv, jj);
            int k = v & 8191;
            int s = v >> 13;
            u32x4 tp = *(const u32x4*)(tab + (size_t)k * FF + 8 * cl);
            u32x4 xu = *(const u32x4*)(xf + (size_t)s * FF + 8 * cl);
            unsigned t0 = valid ? tp.x : 0u;
            unsigned t1 = valid ? tp.y : 0u;
            unsigned t2 = valid ? tp.z : 0u;
            unsigned t3 = valid ? tp.w : 0u;
            a0 = fmaf(blo(t0), blo(xu.x), a0);
            a1 = fmaf(bhi(t0), bhi(xu.x), a1);
            a2 = fmaf(blo(t1), blo(xu.y), a2);
            a3 = fmaf(bhi(t1), bhi(xu.y), a3);
            a4 = fmaf(blo(t2), blo(xu.z), a4);
            a5 = fmaf(bhi(t2), bhi(xu.z), a5);
            a6 = fmaf(blo(t3), blo(xu.w), a6);
            a7 = fmaf(bhi(t3), bhi(xu.w), a7);
        }
    }
    a0 += __shfl_xor(a0, 16); a0 += __shfl_xor(a0, 32);
    a1 += __shfl_xor(a1, 16); a1 += __shfl_xor(a1, 32);
    a2 += __shfl_xor(a2, 16); a2 += __shfl_xor(a2, 32);
    a3 += __shfl_xor(a3, 16); a3 += __shfl_xor(a3, 32);
    a4 += __shfl_xor(a4, 16); a4 += __shfl_xor(a4, 32);
    a5 += __shfl_xor(a5, 16); a5 += __shfl_xor(a5, 32);
    a6 += __shfl_xor(a6, 16); a6 += __shfl_xor(a6, 32);
    a7 += __shfl_xor(a7, 16); a7 += __shfl_xor(a7, 32);
    if (q == 0) {
        bf16x8 pk;
        pk[0] = (bf16)a0; pk[1] = (bf16)a1; pk[2] = (bf16)a2; pk[3] = (bf16)a3;
        pk[4] = (bf16)a4; pk[5] = (bf16)a5; pk[6] = (bf16)a6; pk[7] = (bf16)a7;
        *(bf16x8*)(aggb + (size_t)n * FF + 8 * cl) = pk;
    }
}

// -------- update: transposed-output GEMMs (thread = 1 node x 4-feat spans) ---
__global__ __launch_bounds__(256) void update_kernel(const bf16* __restrict__ aggb,
                                                     const bf16* __restrict__ c2t,
                                                     const float* __restrict__ c2b,
                                                     const bf16* __restrict__ ilt,
                                                     const float* __restrict__ ilb,
                                                     bf16* __restrict__ hb,
                                                     const bf16* __restrict__ c1n,
                                                     bf16* __restrict__ xf_out,
                                                     const bf16* __restrict__ l1t,
                                                     const float* __restrict__ l1b,
                                                     const bf16* __restrict__ l2t,
                                                     const float* __restrict__ l2b,
                                                     float* __restrict__ partial) {
    __shared__ bf16 sB[128 * 136];   // restaged per GEMM
    __shared__ bf16 sT[64 * 136];
    int tid = threadIdx.x;
    int w = tid >> 6, lane = tid & 63, ln = lane & 15, kg = lane >> 4;
    int rowt = blockIdx.x * 64 + w * 16;
    int nrow = rowt + ln;                 // this thread's node (transposed layout)
    int arow = min(nrow, NN - 1);
    bool rowok = nrow < NN;
    // prefetch residual h: node nrow, feats t*16+kg*4 .. +4
    bf16x4 hpre[8];
#pragma unroll
    for (int t = 0; t < 8; t++)
        hpre[t] = *(const bf16x4*)(hb + (size_t)arow * HH + t * 16 + kg * 4);
    for (int idx = tid * 8; idx < 128 * 128; idx += 2048) {
        int n = idx >> 7, k = idx & 127;
        *(bf16x8*)&sB[n * 136 + k] = *(const bf16x8*)(c2t + idx);
    }
    __syncthreads();
    // GEMM1 (Ct): out[feat][node] = conv2^T @ agg^T  (operand-swapped MFMA)
    f32x4 acc[8] = {};
#pragma unroll
    for (int k0 = 0; k0 < 128; k0 += 32) {
        bf16x8 bfrag = *(const bf16x8*)(aggb + (size_t)arow * FF + k0 + kg * 8);
#pragma unroll
        for (int t = 0; t < 8; t++) {
            bf16x8 afrag = *(const bf16x8*)&sB[(t * 16 + ln) * 136 + k0 + kg * 8];
            acc[t] = mfma16(afrag, bfrag, acc[t]);
        }
    }
    // epilogue1: thread holds feats t*16+kg*4+[0..4) of node nrow -> b64 LDS writes
#pragma unroll
    for (int t = 0; t < 8; t++) {
        f32x4 bb = *(const f32x4*)(c2b + t * 16 + kg * 4);
        bf16x4 pk;
#pragma unroll
        for (int r = 0; r < 4; r++) pk[r] = (bf16)sspf(acc[t][r] + bb[r]);
        *(bf16x4*)&sT[(w * 16 + ln) * 136 + t * 16 + kg * 4] = pk;
    }
    __syncthreads();
    for (int idx = tid * 8; idx < 128 * 128; idx += 2048) {
        int n = idx >> 7, k = idx & 127;
        *(bf16x8*)&sB[n * 136 + k] = *(const bf16x8*)(ilt + idx);
    }
    __syncthreads();
    f32x4 acc2[8] = {};
#pragma unroll
    for (int k0 = 0; k0 < 128; k0 += 32) {
        bf16x8 bfrag = *(const bf16x8*)&sT[(w * 16 + ln) * 136 + k0 + kg * 8];
#pragma unroll
        for (int t = 0; t < 8; t++) {
            bf16x8 afrag = *(const bf16x8*)&sB[(t * 16 + ln) * 136 + k0 + kg * 8];
            acc2[t] = mfma16(afrag, bfrag, acc2[t]);
        }
    }
    bool is_last = (c1n == nullptr);
    // epilogue2: residual add, vector stores (own sT rows only -> no barrier needed)
#pragma unroll
    for (int t = 0; t < 8; t++) {
        f32x4 bb = *(const f32x4*)(ilb + t * 16 + kg * 4);
        bf16x4 pk;
#pragma unroll
        for (int r = 0; r < 4; r++)
            pk[r] = (bf16)((float)hpre[t][r] + acc2[t][r] + bb[r]);
        if (rowok && !is_last) *(bf16x4*)(hb + (size_t)nrow * HH + t * 16 + kg * 4) = pk;
        *(bf16x4*)&sT[(w * 16 + ln) * 136 + t * 16 + kg * 4] = pk;
    }
    if (!is_last) {
        // fused next-layer xf = h_new @ conv1_next (same transposed form)
        __syncthreads();
        for (int idx = tid * 8; idx < 128 * 128; idx += 2048) {
            int n = idx >> 7, k = idx & 127;
            *(bf16x8*)&sB[n * 136 + k] = *(const bf16x8*)(c1n + idx);
        }
        __syncthreads();
        f32x4 acc3[8] = {};
#pragma unroll
        for (int k0 = 0; k0 < 128; k0 += 32) {
            bf16x8 bfrag = *(const bf16x8*)&sT[(w * 16 + ln) * 136 + k0 + kg * 8];
#pragma unroll
            for (int t = 0; t < 8; t++) {
                bf16x8 afrag = *(const bf16x8*)&sB[(t * 16 + ln) * 136 + k0 + kg * 8];
                acc3[t] = mfma16(afrag, bfrag, acc3[t]);
            }
        }
#pragma unroll
        for (int t = 0; t < 8; t++) {
            bf16x4 pk;
#pragma unroll
            for (int r = 0; r < 4; r++) pk[r] = (bf16)acc3[t][r];
            if (rowok) *(bf16x4*)(xf_out + (size_t)nrow * FF + t * 16 + kg * 4) = pk;
        }
    } else {
        // fused head: ssp(h@lin1+b)@lin2+b, per-block partial sum (runs once)
        __syncthreads();
        for (int idx = tid * 8; idx < 64 * 128; idx += 2048) {
            int n = idx >> 7, k = idx & 127;
            *(bf16x8*)&sB[n * 136 + k] = *(const bf16x8*)(l1t + idx);
        }
        __syncthreads();
        f32x4 acch[4] = {};
#pragma unroll
        for (int k0 = 0; k0 < 128; k0 += 32) {
            bf16x8 a = *(const bf16x8*)&sT[(w * 16 + ln) * 136 + k0 + kg * 8];
#pragma unroll
            for (int t = 0; t < 4; t++) {
                bf16x8 b = *(const bf16x8*)&sB[(t * 16 + ln) * 136 + k0 + kg * 8];
                acch[t] = mfma16(a, b, acch[t]);
            }
        }
#pragma unroll
        for (int t = 0; t < 4; t++) {
            int colt = t * 16 + ln;
            float bb = l1b[colt];
#pragma unroll
            for (int r = 0; r < 4; r++)
                sT[(w * 16 + kg * 4 + r) * 136 + colt] = (bf16)sspf(acch[t][r] + bb);
        }
        __syncthreads();
        for (int idx = tid * 8; idx < 64 * 64; idx += 2048) {
            int n = idx >> 6, k = idx & 63;
            *(bf16x8*)&sB[n * 136 + k] = *(const bf16x8*)(l2t + idx);
        }
        __syncthreads();
        f32x4 acc2h[4] = {};
#pragma unroll
        for (int k0 = 0; k0 < 64; k0 += 32) {
            bf16x8 a = *(const bf16x8*)&sT[(w * 16 + ln) * 136 + k0 + kg * 8];
#pragma unroll
            for (int t = 0; t < 4; t++) {
                bf16x8 b = *(const bf16x8*)&sB[(t * 16 + ln) * 136 + k0 + kg * 8];
                acc2h[t] = mfma16(a, b, acc2h[t]);
            }
        }
        __syncthreads();   // all sT reads done; reuse as f32 scratch
        float* sPart = (float*)sT;
#pragma unroll
        for (int t = 0; t < 4; t++) {
            int colt = t * 16 + ln;
            float bb = l2b[colt];
            float v = 0.f;
#pragma unroll
            for (int r = 0; r < 4; r++) {
                int orow = rowt + kg * 4 + r;
                if (orow < NN) v += acc2h[t][r] + bb;
            }
            v += __shfl_xor(v, 16);
            v += __shfl_xor(v, 32);
            if (kg == 0) sPart[w * 64 + colt] = v;
        }
        __syncthreads();
        if (tid < 64) {
            float s = sPart[tid] + sPart[64 + tid] + sPart[128 + tid] + sPart[192 + tid];
            partial[blockIdx.x * 64 + tid] = s;
        }
    }
}

__global__ __launch_bounds__(64) void final_kernel(const float* __restrict__ partial,
                                                   const float* __restrict__ rw,
                                                   const float* __restrict__ rb,
                                                   float* __restrict__ out) {
    __shared__ float sv[64];
    int j = threadIdx.x;
    float s = 0.f;
    for (int b = 0; b < NBLK; b++) s += partial[b * 64 + j];
    sv[j] = s;
    __syncthreads();
    if (j < OUT_DIM) {
        float o = rb[j];
        for (int i = 0; i < H2D; i++) o += sv[i] * rw[i * OUT_DIM + j];
        out[j] = o;
    }
}

// -------- launch -------------------------------------------------------------
extern "C" void kernel_launch(void* const* d_in, const int* in_sizes, int n_in,
                              void* d_out, int out_size, void* d_ws, size_t ws_size,
                              hipStream_t stream) {
    const int*   x_atoms    = (const int*)d_in[0];
    const int*   edge_index = (const int*)d_in[1];
    const float* edge_attr  = (const float*)d_in[2];
    const float* embedding  = (const float*)d_in[3];
    const float* mlp_w1     = (const float*)d_in[4];
    const float* mlp_b1     = (const float*)d_in[5];
    const float* mlp_w2     = (const float*)d_in[6];
    const float* mlp_b2     = (const float*)d_in[7];
    const float* conv1_w    = (const float*)d_in[8];
    const float* conv2_w    = (const float*)d_in[9];
    const float* conv2_b    = (const float*)d_in[10];
    const float* int_lin_w  = (const float*)d_in[11];
    const float* int_lin_b  = (const float*)d_in[12];
    const float* lin1_w     = (const float*)d_in[13];
    const float* lin1_b     = (const float*)d_in[14];
    const float* lin2_w     = (const float*)d_in[15];
    const float* lin2_b     = (const float*)d_in[16];
    const float* readout_w  = (const float*)d_in[17];
    const float* readout_b  = (const float*)d_in[18];

    char* ws = (char*)d_ws;
    bf16*  hb      = (bf16*)(ws + 0);              // 12,800,000
    bf16*  xfA     = (bf16*)(ws + 12800000);       // 12,800,000
    bf16*  xfB     = (bf16*)(ws + 25600000);       // 12,800,000
    bf16*  aggb    = (bf16*)(ws + 38400000);       // 12,800,000
    float* partial = (float*)(ws + 51200000);      // 200,192
    size_t wb = 51400192;
    bf16* c1t = (bf16*)(ws + wb);                  // 196,608
    bf16* c2t = (bf16*)(ws + wb + 196608);
    bf16* ilt = (bf16*)(ws + wb + 393216);
    bf16* w1t = (bf16*)(ws + wb + 589824);         // 98,304
    bf16* w2t = (bf16*)(ws + wb + 688128);         // 196,608
    bf16* l1t = (bf16*)(ws + wb + 884736);         // 16,384
    bf16* l2t = (bf16*)(ws + wb + 901120);         // 8,192 -> ends 52,309,504
    int*   d_hist = (int*)(ws + 52309504);         // 200,000
    int*   d_rs   = (int*)(ws + 52509504);         // 200,000
    int*   d_bcur = (int*)(ws + 52709504);         // 1,024 (bucket_cur)
    int*   d_bsum = (int*)(ws + 52710528);         // 1,024
    int*   d_es   = (int*)(ws + 52711552);         // 3,200,000 -> 55,911,552
    bf16*  tab    = (bf16*)(ws + 55911552);        // 6*4097*128*2 = 6,292,992 -> 62,204,544
    int2*  d_tmp8 = (int2*)(ws + 62204544);        // 6,400,000 -> 68,604,544

    SetupArgs sa;
    sa.conv1_w = conv1_w; sa.conv2_w = conv2_w; sa.int_lin_w = int_lin_w;
    sa.mlp_w1 = mlp_w1; sa.mlp_w2 = mlp_w2; sa.lin1_w = lin1_w; sa.lin2_w = lin2_w;
    sa.c1t = c1t; sa.c2t = c2t; sa.ilt = ilt; sa.w1t = w1t; sa.w2t = w2t;
    sa.l1t = l1t; sa.l2t = l2t;
    sa.mlp_b1 = mlp_b1; sa.mlp_b2 = mlp_b2;
    sa.edge_index = edge_index; sa.edge_attr = edge_attr;
    sa.hist = d_hist; sa.bsum = d_bsum; sa.rs = d_rs; sa.bcur = d_bcur;
    sa.tmp8 = d_tmp8; sa.es = d_es;
    sa.x_atoms = x_atoms; sa.emb = embedding;
    sa.tab = tab; sa.hb = hb; sa.xf = xfA;
    void* kp[] = { (void*)&sa };
    hipLaunchCooperativeKernel((const void*)setup_kernel, dim3(NB), dim3(256), kp, 0, stream);

    bf16* xf_in = xfA;
    bf16* xf_out = xfB;
    for (int l = 0; l < LL; l++) {
        edge_kernel<<<NN / 4, 256, 0, stream>>>(d_es, d_rs, d_hist, xf_in,
                                                tab + (size_t)l * (NK + 1) * FF, aggb);
        const bf16* c1n = (l + 1 < LL) ? (c1t + (size_t)(l + 1) * FF * HH) : nullptr;
        update_kernel<<<NBLK, 256, 0, stream>>>(aggb, c2t + (size_t)l * HH * FF,
                                                conv2_b + l * HH,
                                                ilt + (size_t)l * HH * HH, int_lin_b + l * HH,
                                                hb, c1n, xf_out,
                                                l1t, lin1_b, l2t, lin2_b, partial);
        bf16* tmp = xf_in; xf_in = xf_out; xf_out = tmp;
    }
    final_kernel<<<1, 64, 0, stream>>>(partial, readout_w, readout_b, (float*)d_out);
}

// Round 14
// 628.297 us; speedup vs baseline: 1.3987x; 1.3987x over previous
//
#include <hip/hip_runtime.h>
#include <hip/hip_bf16.h>
#include <math.h>

#define NN 50000
#define EE 800000
#define HH 128
#define FF 128
#define GG 50
#define LL 6
#define H2D 64
#define OUT_DIM 12
#define NK 4096          // nearest-neighbor table intervals; knots 0..NK (4097)
#define NBLK 782         // ceil(NN/64)
#define SB 196           // scan blocks: ceil(NN/256)
#define NBUK 196         // scatter buckets: 256 nodes each

typedef __bf16 bf16;
typedef __attribute__((ext_vector_type(8))) __bf16 bf16x8;
typedef __attribute__((ext_vector_type(4))) __bf16 bf16x4;
typedef __attribute__((ext_vector_type(4))) float f32x4;
typedef __attribute__((ext_vector_type(4))) unsigned u32x4;

#define DEV __device__ __forceinline__

// fast shifted-softplus: hw v_exp/v_log, err ~1e-6 << bf16 rounding
DEV float sspf(float x) {
    return fmaxf(x, 0.f) + __logf(1.f + __expf(-fabsf(x))) - 0.69314718055994531f;
}

DEV f32x4 mfma16(bf16x8 a, bf16x8 b, f32x4 c) {
    return __builtin_amdgcn_mfma_f32_16x16x32_bf16(a, b, c, 0, 0, 0);
}

DEV float blo(unsigned u) { return __uint_as_float(u << 16); }
DEV float bhi(unsigned u) { return __uint_as_float(u & 0xffff0000u); }

// -------- prep: transpose all weights to [n][k] bf16 (+ zero hist) -----------
struct PrepArgs {
    const float *conv1_w, *conv2_w, *int_lin_w, *mlp_w1, *mlp_w2, *lin1_w, *lin2_w;
    bf16 *c1t, *c2t, *ilt, *w1t, *w2t, *l1t, *l2t;
    int* hist;
};

__global__ void prep_kernel(PrepArgs p) {
    int j = blockIdx.x;
    // fused hist zeroing (grid-stride over all 32 blocks)
    for (int i = blockIdx.x * 256 + threadIdx.x; i < NN; i += 32 * 256) p.hist[i] = 0;
    const float* src = nullptr; bf16* dst = nullptr; int R = 0, C = 0, K = 0;
    if (j < 30) {
        int l = j / 5, m = j % 5;
        switch (m) {
            case 0: src = p.conv1_w + l * HH * FF;   dst = p.c1t + l * FF * HH;  R = HH; C = FF; K = HH; break;
            case 1: src = p.conv2_w + l * FF * HH;   dst = p.c2t + l * HH * FF;  R = FF; C = HH; K = FF; break;
            case 2: src = p.int_lin_w + l * HH * HH; dst = p.ilt + l * HH * HH;  R = HH; C = HH; K = HH; break;
            case 3: src = p.mlp_w1 + l * GG * FF;    dst = p.w1t + l * FF * 64;  R = GG; C = FF; K = 64; break;
            case 4: src = p.mlp_w2 + l * FF * FF;    dst = p.w2t + l * FF * FF;  R = FF; C = FF; K = FF; break;
        }
    } else if (j == 30) { src = p.lin1_w; dst = p.l1t; R = HH;  C = H2D; K = HH; }
    else                { src = p.lin2_w; dst = p.l2t; R = H2D; C = H2D; K = H2D; }
    int total = C * K;
    for (int idx = threadIdx.x; idx < total; idx += blockDim.x) {
        int c = idx / K, r = idx - c * K;
        dst[idx] = (r < R) ? (bf16)src[r * C + c] : (bf16)0.f;
    }
}

// -------- table build via MFMA: T[l][r][:] = (ssp(g(d)@W1+b1)@W2+b2)*C(d) ----
__global__ __launch_bounds__(256) void table_kernel(const bf16* __restrict__ w1t,
                                                    const bf16* __restrict__ w2t,
                                                    const float* __restrict__ mlp_b1,
                                                    const float* __restrict__ mlp_b2,
                                                    bf16* __restrict__ tab) {
    __shared__ bf16 sW1[128 * 72];
    __shared__ bf16 sW2[128 * 136];
    __shared__ bf16 sT1[64 * 136];
    int tid = threadIdx.x;
    int l = blockIdx.x / 65, rb = blockIdx.x % 65;
    const bf16* W1 = w1t + (size_t)l * 128 * 64;
    const bf16* W2 = w2t + (size_t)l * 128 * 128;
    for (int idx = tid * 8; idx < 128 * 64; idx += 2048) {
        int n = idx >> 6, k = idx & 63;
        *(bf16x8*)&sW1[n * 72 + k] = *(const bf16x8*)(W1 + idx);
    }
    for (int idx = tid * 8; idx < 128 * 128; idx += 2048) {
        int n = idx >> 7, k = idx & 127;
        *(bf16x8*)&sW2[n * 136 + k] = *(const bf16x8*)(W2 + idx);
    }
    int w = tid >> 6, lane = tid & 63, ln = lane & 15, kg = lane >> 4;
    int rowt = rb * 64 + w * 16;
    float d1 = (float)min(rowt + ln, NK) * (10.f / NK);
    const float step = 10.f / 49.f;
    const float coeff = -0.5f / (step * step);
    __syncthreads();
    // GEMM1: in-register gaussian basis @ W1
    f32x4 acc[8] = {};
#pragma unroll
    for (int k0 = 0; k0 < 64; k0 += 32) {
        bf16x8 a;
#pragma unroll
        for (int jj = 0; jj < 8; jj++) {
            int g = k0 + kg * 8 + jj;
            float diff = d1 - g * step;
            float v = (g < GG) ? __expf(coeff * diff * diff) : 0.f;
            a[jj] = (bf16)v;
        }
#pragma unroll
        for (int t = 0; t < 8; t++) {
            bf16x8 b = *(const bf16x8*)&sW1[(t * 16 + ln) * 72 + k0 + kg * 8];
            acc[t] = mfma16(a, b, acc[t]);
        }
    }
    const float* b1 = mlp_b1 + l * FF;
#pragma unroll
    for (int t = 0; t < 8; t++) {
        int colt = t * 16 + ln;
        float bb = b1[colt];
#pragma unroll
        for (int r = 0; r < 4; r++)
            sT1[(w * 16 + kg * 4 + r) * 136 + colt] = (bf16)sspf(acc[t][r] + bb);
    }
    __syncthreads();
    f32x4 acc2[8] = {};
#pragma unroll
    for (int k0 = 0; k0 < 128; k0 += 32) {
        bf16x8 a = *(const bf16x8*)&sT1[(w * 16 + ln) * 136 + k0 + kg * 8];
#pragma unroll
        for (int t = 0; t < 8; t++) {
            bf16x8 b = *(const bf16x8*)&sW2[(t * 16 + ln) * 136 + k0 + kg * 8];
            acc2[t] = mfma16(a, b, acc2[t]);
        }
    }
    const float* b2 = mlp_b2 + l * FF;
    float Cw[4]; int rrow[4];
#pragma unroll
    for (int r = 0; r < 4; r++) {
        int rr = rowt + kg * 4 + r;
        rrow[r] = rr;
        float dd = (float)min(rr, NK) * (10.f / NK);
        Cw[r] = 0.5f * (cosf(dd * 0.31415926535897932f) + 1.f);
    }
#pragma unroll
    for (int t = 0; t < 8; t++) {
        int colt = t * 16 + ln;
        float bb = b2[colt];
#pragma unroll
        for (int r = 0; r < 4; r++) {
            if (rrow[r] <= NK)
                tab[((size_t)l * (NK + 1) + rrow[r]) * FF + colt] = (bf16)((acc2[t][r] + bb) * Cw[r]);
        }
    }
}

// -------- edge sort by dst: histogram / hierarchical scan --------------------
__global__ void hist_kernel(const int* __restrict__ eidx, int* __restrict__ hist) {
    int e = blockIdx.x * 256 + threadIdx.x;
    if (e < EE) atomicAdd(&hist[eidx[EE + e]], 1);
}

__global__ __launch_bounds__(256) void scanA_kernel(const int* __restrict__ hist,
                                                    int* __restrict__ bsum) {
    __shared__ int red[256];
    int t = threadIdx.x;
    int i = blockIdx.x * 256 + t;
    int v = (i < NN) ? hist[i] : 0;
    red[t] = v;
    __syncthreads();
    for (int off = 128; off > 0; off >>= 1) {
        if (t < off) red[t] += red[t + off];
        __syncthreads();
    }
    if (t == 0) bsum[blockIdx.x] = red[0];
}

__global__ __launch_bounds__(256) void scanB_kernel(int* __restrict__ bsum,
                                                    int* __restrict__ done) {
    __shared__ int buf[256];
    int t = threadIdx.x;
    if (t == 0) *done = 0;                 // zero last-block ticket (fused)
    int v = (t < SB) ? bsum[t] : 0;
    buf[t] = v;
    __syncthreads();
    for (int off = 1; off < 256; off <<= 1) {
        int y = (t >= off) ? buf[t - off] : 0;
        __syncthreads();
        buf[t] += y;
        __syncthreads();
    }
    if (t < SB) bsum[t] = buf[t] - v;   // exclusive
}

__global__ __launch_bounds__(256) void scanC_kernel(const int* __restrict__ hist,
                                                    const int* __restrict__ bsum,
                                                    int* __restrict__ rs,
                                                    int* __restrict__ bucket_cur) {
    __shared__ int buf[256];
    int t = threadIdx.x;
    int i = blockIdx.x * 256 + t;
    int v = (i < NN) ? hist[i] : 0;
    buf[t] = v;
    __syncthreads();
    for (int off = 1; off < 256; off <<= 1) {
        int y = (t >= off) ? buf[t - off] : 0;
        __syncthreads();
        buf[t] += y;
        __syncthreads();
    }
    if (i < NN) {
        int ex = buf[t] - v + bsum[blockIdx.x];
        rs[i] = ex;
        if ((i & 255) == 0) bucket_cur[i >> 8] = ex;   // bucket base (fused bukinit)
    }
}

// -------- bucketed two-pass scatter (kills 64B-line write amplification) -----
// pass 1: 196 blocks x 4096 edges -> bucket-grouped tmp (int2: packed, dst)
__global__ __launch_bounds__(256) void scat1_kernel(const float* __restrict__ eattr,
                                                    const int* __restrict__ eidx,
                                                    int* __restrict__ bucket_cur,
                                                    int2* __restrict__ tmp8) {
    __shared__ int cnt[NBUK];
    __shared__ int res[NBUK];
    int t = threadIdx.x;
    for (int i = t; i < NBUK; i += 256) cnt[i] = 0;
    __syncthreads();
    int e0 = blockIdx.x * 4096;
    int pv[16], dd[16], bk[16];
#pragma unroll
    for (int i = 0; i < 16; i++) {
        int e = e0 + i * 256 + t;
        if (e < EE) {
            int d = eidx[EE + e];
            int k = (int)(eattr[e] * ((float)NK / 10.f) + 0.5f);
            k = min(k, NK);
            pv[i] = k | (eidx[e] << 13);
            dd[i] = d;
            bk[i] = d >> 8;
            atomicAdd(&cnt[bk[i]], 1);
        } else bk[i] = -1;
    }
    __syncthreads();
    for (int i = t; i < NBUK; i += 256) {
        int c = cnt[i];
        res[i] = (c > 0) ? atomicAdd(&bucket_cur[i], c) : 0;
        cnt[i] = 0;          // reuse as local rank counter
    }
    __syncthreads();
#pragma unroll
    for (int i = 0; i < 16; i++) {
        if (bk[i] >= 0) {
            int rank = atomicAdd(&cnt[bk[i]], 1);
            int2 v; v.x = pv[i]; v.y = dd[i];
            tmp8[res[bk[i]] + rank] = v;
        }
    }
}

// pass 2: one block per bucket -> final dst-sorted es (dense 16KB window)
__global__ __launch_bounds__(256) void scat2_kernel(const int* __restrict__ rs,
                                                    const int2* __restrict__ tmp8,
                                                    int* __restrict__ es) {
    __shared__ int off[256];
    __shared__ int loc[256];
    int b = blockIdx.x, t = threadIdx.x;
    int nb0 = b * 256;
    int nnb = min(256, NN - nb0);          // nodes in this bucket
    int base = rs[nb0];
    int end = (nb0 + 256 < NN) ? rs[nb0 + 256] : EE;
    loc[t] = 0;
    if (t < nnb) off[t] = rs[nb0 + t] - base;
    __syncthreads();
    for (int e = base + t; e < end; e += 256) {
        int2 v = tmp8[e];
        int nl = v.y - nb0;
        int rank = atomicAdd(&loc[nl], 1);
        es[base + off[nl] + rank] = v.x;
    }
}

// -------- xf0: hb = embedding[x_atoms]; xf = hb @ conv1_w (fused, layer 0) ---
__global__ __launch_bounds__(256) void xf0_kernel(const int* __restrict__ x_atoms,
                                                  const float* __restrict__ emb,
                                                  const bf16* __restrict__ c1t,
                                                  bf16* __restrict__ hb,
                                                  bf16* __restrict__ xf) {
    __shared__ bf16 sB[128 * 136];
    int tid = threadIdx.x;
    for (int idx = tid * 8; idx < 128 * 128; idx += 2048) {
        int n = idx >> 7, k = idx & 127;
        *(bf16x8*)&sB[n * 136 + k] = *(const bf16x8*)(c1t + idx);
    }
    int w = tid >> 6, lane = tid & 63, ln = lane & 15, kg = lane >> 4;
    int rowt = blockIdx.x * 64 + w * 16;
    int nrow = rowt + ln;
    int arow = min(nrow, NN - 1);
    bool rowok = nrow < NN;
    int atom = x_atoms[arow];
    __syncthreads();
    f32x4 acc[8] = {};
#pragma unroll
    for (int k0 = 0; k0 < 128; k0 += 32) {
        const float* ep = emb + (size_t)atom * HH + k0 + kg * 8;
        f32x4 u0 = *(const f32x4*)ep;
        f32x4 u1 = *(const f32x4*)(ep + 4);
        bf16x8 a;
#pragma unroll
        for (int q = 0; q < 4; q++) { a[q] = (bf16)u0[q]; a[q + 4] = (bf16)u1[q]; }
        if (rowok) *(bf16x8*)(hb + (size_t)nrow * HH + k0 + kg * 8) = a;
#pragma unroll
        for (int t = 0; t < 8; t++) {
            bf16x8 b = *(const bf16x8*)&sB[(t * 16 + ln) * 136 + k0 + kg * 8];
            acc[t] = mfma16(a, b, acc[t]);
        }
    }
#pragma unroll
    for (int t = 0; t < 8; t++) {
        int colt = t * 16 + ln;
#pragma unroll
        for (int r = 0; r < 4; r++) {
            int orow = rowt + kg * 4 + r;
            if (orow < NN) xf[orow * FF + colt] = (bf16)acc[t][r];
        }
    }
}

// -------- edge kernel: CSR, one wave/node, nearest-knot, 4 edges/iter --------
__global__ __launch_bounds__(256) void edge_kernel(const int* __restrict__ es,
                                                   const int* __restrict__ rs,
                                                   const int* __restrict__ hist,
                                                   const bf16* __restrict__ xf,
                                                   const bf16* __restrict__ tab,
                                                   bf16* __restrict__ aggb) {
    int tid = threadIdx.x;
    int w = tid >> 6, lane = tid & 63;
    int q = lane >> 4, cl = lane & 15;      // quarter q handles edge 4j+q; lane covers ch [8cl,8cl+8)
    int n = blockIdx.x * 4 + w;
    int start = rs[n], deg = hist[n];
    float a0 = 0.f, a1 = 0.f, a2 = 0.f, a3 = 0.f;
    float a4 = 0.f, a5 = 0.f, a6 = 0.f, a7 = 0.f;
    for (int base = 0; base < deg; base += 64) {
        int cnt = min(deg - base, 64);
        int pv = (lane < cnt) ? es[start + base + lane] : 0;
        int iters = (cnt + 3) >> 2;
#pragma unroll 4
        for (int j = 0; j < iters; j++) {
            int jj = 4 * j + q;
            bool valid = jj < cnt;
            int v = __shfl(pv, jj);
            int k = v & 8191;
            int s = v >> 13;
            u32x4 tp = *(const u32x4*)(tab + (size_t)k * FF + 8 * cl);
            u32x4 xu = *(const u32x4*)(xf + (size_t)s * FF + 8 * cl);
            unsigned t0 = valid ? tp.x : 0u;
            unsigned t1 = valid ? tp.y : 0u;
            unsigned t2 = valid ? tp.z : 0u;
            unsigned t3 = valid ? tp.w : 0u;
            a0 = fmaf(blo(t0), blo(xu.x), a0);
            a1 = fmaf(bhi(t0), bhi(xu.x), a1);
            a2 = fmaf(blo(t1), blo(xu.y), a2);
            a3 = fmaf(bhi(t1), bhi(xu.y), a3);
            a4 = fmaf(blo(t2), blo(xu.z), a4);
            a5 = fmaf(bhi(t2), bhi(xu.z), a5);
            a6 = fmaf(blo(t3), blo(xu.w), a6);
            a7 = fmaf(bhi(t3), bhi(xu.w), a7);
        }
    }
    a0 += __shfl_xor(a0, 16); a0 += __shfl_xor(a0, 32);
    a1 += __shfl_xor(a1, 16); a1 += __shfl_xor(a1, 32);
    a2 += __shfl_xor(a2, 16); a2 += __shfl_xor(a2, 32);
    a3 += __shfl_xor(a3, 16); a3 += __shfl_xor(a3, 32);
    a4 += __shfl_xor(a4, 16); a4 += __shfl_xor(a4, 32);
    a5 += __shfl_xor(a5, 16); a5 += __shfl_xor(a5, 32);
    a6 += __shfl_xor(a6, 16); a6 += __shfl_xor(a6, 32);
    a7 += __shfl_xor(a7, 16); a7 += __shfl_xor(a7, 32);
    if (q == 0) {
        bf16x8 pk;
        pk[0] = (bf16)a0; pk[1] = (bf16)a1; pk[2] = (bf16)a2; pk[3] = (bf16)a3;
        pk[4] = (bf16)a4; pk[5] = (bf16)a5; pk[6] = (bf16)a6; pk[7] = (bf16)a7;
        *(bf16x8*)(aggb + (size_t)n * FF + 8 * cl) = pk;
    }
}

// -------- update: transposed-output GEMMs (thread = 1 node x 4-feat spans) ---
__global__ __launch_bounds__(256) void update_kernel(const bf16* __restrict__ aggb,
                                                     const bf16* __restrict__ c2t,
                                                     const float* __restrict__ c2b,
                                                     const bf16* __restrict__ ilt,
                                                     const float* __restrict__ ilb,
                                                     bf16* __restrict__ hb,
                                                     const bf16* __restrict__ c1n,
                                                     bf16* __restrict__ xf_out,
                                                     const bf16* __restrict__ l1t,
                                                     const float* __restrict__ l1b,
                                                     const bf16* __restrict__ l2t,
                                                     const float* __restrict__ l2b,
                                                     float* __restrict__ partial,
                                                     const float* __restrict__ rw,
                                                     const float* __restrict__ rb,
                                                     float* __restrict__ out,
                                                     int* __restrict__ done) {
    __shared__ bf16 sB[128 * 136];   // restaged per GEMM
    __shared__ bf16 sT[64 * 136];
    __shared__ int lastf;
    int tid = threadIdx.x;
    int w = tid >> 6, lane = tid & 63, ln = lane & 15, kg = lane >> 4;
    int rowt = blockIdx.x * 64 + w * 16;
    int nrow = rowt + ln;                 // this thread's node (transposed layout)
    int arow = min(nrow, NN - 1);
    bool rowok = nrow < NN;
    // prefetch residual h: node nrow, feats t*16+kg*4 .. +4
    bf16x4 hpre[8];
#pragma unroll
    for (int t = 0; t < 8; t++)
        hpre[t] = *(const bf16x4*)(hb + (size_t)arow * HH + t * 16 + kg * 4);
    for (int idx = tid * 8; idx < 128 * 128; idx += 2048) {
        int n = idx >> 7, k = idx & 127;
        *(bf16x8*)&sB[n * 136 + k] = *(const bf16x8*)(c2t + idx);
    }
    __syncthreads();
    // GEMM1 (Ct): out[feat][node] = conv2^T @ agg^T  (operand-swapped MFMA)
    f32x4 acc[8] = {};
#pragma unroll
    for (int k0 = 0; k0 < 128; k0 += 32) {
        bf16x8 bfrag = *(const bf16x8*)(aggb + (size_t)arow * FF + k0 + kg * 8);
#pragma unroll
        for (int t = 0; t < 8; t++) {
            bf16x8 afrag = *(const bf16x8*)&sB[(t * 16 + ln) * 136 + k0 + kg * 8];
            acc[t] = mfma16(afrag, bfrag, acc[t]);
        }
    }
    // epilogue1: thread holds feats t*16+kg*4+[0..4) of node nrow -> b64 LDS writes
#pragma unroll
    for (int t = 0; t < 8; t++) {
        f32x4 bb = *(const f32x4*)(c2b + t * 16 + kg * 4);
        bf16x4 pk;
#pragma unroll
        for (int r = 0; r < 4; r++) pk[r] = (bf16)sspf(acc[t][r] + bb[r]);
        *(bf16x4*)&sT[(w * 16 + ln) * 136 + t * 16 + kg * 4] = pk;
    }
    __syncthreads();
    for (int idx = tid * 8; idx < 128 * 128; idx += 2048) {
        int n = idx >> 7, k = idx & 127;
        *(bf16x8*)&sB[n * 136 + k] = *(const bf16x8*)(ilt + idx);
    }
    __syncthreads();
    f32x4 acc2[8] = {};
#pragma unroll
    for (int k0 = 0; k0 < 128; k0 += 32) {
        bf16x8 bfrag = *(const bf16x8*)&sT[(w * 16 + ln) * 136 + k0 + kg * 8];
#pragma unroll
        for (int t = 0; t < 8; t++) {
            bf16x8 afrag = *(const bf16x8*)&sB[(t * 16 + ln) * 136 + k0 + kg * 8];
            acc2[t] = mfma16(afrag, bfrag, acc2[t]);
        }
    }
    bool is_last = (c1n == nullptr);
    // epilogue2: residual add, vector stores (own sT rows only -> no barrier needed)
#pragma unroll
    for (int t = 0; t < 8; t++) {
        f32x4 bb = *(const f32x4*)(ilb + t * 16 + kg * 4);
        bf16x4 pk;
#pragma unroll
        for (int r = 0; r < 4; r++)
            pk[r] = (bf16)((float)hpre[t][r] + acc2[t][r] + bb[r]);
        if (rowok && !is_last) *(bf16x4*)(hb + (size_t)nrow * HH + t * 16 + kg * 4) = pk;
        *(bf16x4*)&sT[(w * 16 + ln) * 136 + t * 16 + kg * 4] = pk;
    }
    if (!is_last) {
        // fused next-layer xf = h_new @ conv1_next (same transposed form)
        __syncthreads();
        for (int idx = tid * 8; idx < 128 * 128; idx += 2048) {
            int n = idx >> 7, k = idx & 127;
            *(bf16x8*)&sB[n * 136 + k] = *(const bf16x8*)(c1n + idx);
        }
        __syncthreads();
        f32x4 acc3[8] = {};
#pragma unroll
        for (int k0 = 0; k0 < 128; k0 += 32) {
            bf16x8 bfrag = *(const bf16x8*)&sT[(w * 16 + ln) * 136 + k0 + kg * 8];
#pragma unroll
            for (int t = 0; t < 8; t++) {
                bf16x8 afrag = *(const bf16x8*)&sB[(t * 16 + ln) * 136 + k0 + kg * 8];
                acc3[t] = mfma16(afrag, bfrag, acc3[t]);
            }
        }
#pragma unroll
        for (int t = 0; t < 8; t++) {
            bf16x4 pk;
#pragma unroll
            for (int r = 0; r < 4; r++) pk[r] = (bf16)acc3[t][r];
            if (rowok) *(bf16x4*)(xf_out + (size_t)nrow * FF + t * 16 + kg * 4) = pk;
        }
    } else {
        // fused head: ssp(h@lin1+b)@lin2+b, per-block partial sum (runs once)
        __syncthreads();
        for (int idx = tid * 8; idx < 64 * 128; idx += 2048) {
            int n = idx >> 7, k = idx & 127;
            *(bf16x8*)&sB[n * 136 + k] = *(const bf16x8*)(l1t + idx);
        }
        __syncthreads();
        f32x4 acch[4] = {};
#pragma unroll
        for (int k0 = 0; k0 < 128; k0 += 32) {
            bf16x8 a = *(const bf16x8*)&sT[(w * 16 + ln) * 136 + k0 + kg * 8];
#pragma unroll
            for (int t = 0; t < 4; t++) {
                bf16x8 b = *(const bf16x8*)&sB[(t * 16 + ln) * 136 + k0 + kg * 8];
                acch[t] = mfma16(a, b, acch[t]);
            }
        }
#pragma unroll
        for (int t = 0; t < 4; t++) {
            int colt = t * 16 + ln;
            float bb = l1b[colt];
#pragma unroll
            for (int r = 0; r < 4; r++)
                sT[(w * 16 + kg * 4 + r) * 136 + colt] = (bf16)sspf(acch[t][r] + bb);
        }
        __syncthreads();
        for (int idx = tid * 8; idx < 64 * 64; idx += 2048) {
            int n = idx >> 6, k = idx & 63;
            *(bf16x8*)&sB[n * 136 + k] = *(const bf16x8*)(l2t + idx);
        }
        __syncthreads();
        f32x4 acc2h[4] = {};
#pragma unroll
        for (int k0 = 0; k0 < 64; k0 += 32) {
            bf16x8 a = *(const bf16x8*)&sT[(w * 16 + ln) * 136 + k0 + kg * 8];
#pragma unroll
            for (int t = 0; t < 4; t++) {
                bf16x8 b = *(const bf16x8*)&sB[(t * 16 + ln) * 136 + k0 + kg * 8];
                acc2h[t] = mfma16(a, b, acc2h[t]);
            }
        }
        __syncthreads();   // all sT reads done; reuse as f32 scratch
        float* sPart = (float*)sT;
#pragma unroll
        for (int t = 0; t < 4; t++) {
            int colt = t * 16 + ln;
            float bb = l2b[colt];
            float v = 0.f;
#pragma unroll
            for (int r = 0; r < 4; r++) {
                int orow = rowt + kg * 4 + r;
                if (orow < NN) v += acc2h[t][r] + bb;
            }
            v += __shfl_xor(v, 16);
            v += __shfl_xor(v, 32);
            if (kg == 0) sPart[w * 64 + colt] = v;
        }
        __syncthreads();
        if (tid < 64) {
            float s = sPart[tid] + sPart[64 + tid] + sPart[128 + tid] + sPart[192 + tid];
            partial[blockIdx.x * 64 + tid] = s;
        }
        // last-block final reduction (replaces final_kernel)
        __threadfence();
        if (tid == 0) lastf = (atomicAdd(done, 1) == NBLK - 1) ? 1 : 0;
        __syncthreads();
        if (lastf) {
            __threadfence();
            if (tid < 64) {
                float s2 = 0.f;
                for (int b = 0; b < NBLK; b++) s2 += partial[b * 64 + tid];
                sPart[tid] = s2;
            }
            __syncthreads();
            if (tid < OUT_DIM) {
                float o = rb[tid];
                for (int i = 0; i < H2D; i++) o += sPart[i] * rw[i * OUT_DIM + tid];
                out[tid] = o;
            }
        }
    }
}

// -------- launch -------------------------------------------------------------
extern "C" void kernel_launch(void* const* d_in, const int* in_sizes, int n_in,
                              void* d_out, int out_size, void* d_ws, size_t ws_size,
                              hipStream_t stream) {
    const int*   x_atoms    = (const int*)d_in[0];
    const int*   edge_index = (const int*)d_in[1];
    const float* edge_attr  = (const float*)d_in[2];
    const float* embedding  = (const float*)d_in[3];
    const float* mlp_w1     = (const float*)d_in[4];
    const float* mlp_b1     = (const float*)d_in[5];
    const float* mlp_w2     = (const float*)d_in[6];
    const float* mlp_b2     = (const float*)d_in[7];
    const float* conv1_w    = (const float*)d_in[8];
    const float* conv2_w    = (const float*)d_in[9];
    const float* conv2_b    = (const float*)d_in[10];
    const float* int_lin_w  = (const float*)d_in[11];
    const float* int_lin_b  = (const float*)d_in[12];
    const float* lin1_w     = (const float*)d_in[13];
    const float* lin1_b     = (const float*)d_in[14];
    const float* lin2_w     = (const float*)d_in[15];
    const float* lin2_b     = (const float*)d_in[16];
    const float* readout_w  = (const float*)d_in[17];
    const float* readout_b  = (const float*)d_in[18];

    char* ws = (char*)d_ws;
    bf16*  hb      = (bf16*)(ws + 0);              // 12,800,000
    bf16*  xfA     = (bf16*)(ws + 12800000);       // 12,800,000
    bf16*  xfB     = (bf16*)(ws + 25600000);       // 12,800,000
    bf16*  aggb    = (bf16*)(ws + 38400000);       // 12,800,000
    float* partial = (float*)(ws + 51200000);      // 200,192
    size_t wb = 51400192;
    bf16* c1t = (bf16*)(ws + wb);                  // 196,608
    bf16* c2t = (bf16*)(ws + wb + 196608);
    bf16* ilt = (bf16*)(ws + wb + 393216);
    bf16* w1t = (bf16*)(ws + wb + 589824);         // 98,304
    bf16* w2t = (bf16*)(ws + wb + 688128);         // 196,608
    bf16* l1t = (bf16*)(ws + wb + 884736);         // 16,384
    bf16* l2t = (bf16*)(ws + wb + 901120);         // 8,192 -> ends 52,309,504
    int*   d_hist = (int*)(ws + 52309504);         // 200,000
    int*   d_rs   = (int*)(ws + 52509504);         // 200,000
    int*   d_bcur = (int*)(ws + 52709504);         // 1,024 (bucket_cur)
    int*   d_bsum = (int*)(ws + 52710528);         // 1,020
    int*   d_done = (int*)(ws + 52711548);         // 4
    int*   d_es   = (int*)(ws + 52711552);         // 3,200,000 -> 55,911,552
    bf16*  tab    = (bf16*)(ws + 55911552);        // 6*4097*128*2 = 6,292,992 -> 62,204,544
    int2*  d_tmp8 = (int2*)(ws + 62204544);        // 6,400,000 -> 68,604,544

    PrepArgs pa = { conv1_w, conv2_w, int_lin_w, mlp_w1, mlp_w2, lin1_w, lin2_w,
                    c1t, c2t, ilt, w1t, w2t, l1t, l2t, d_hist };
    prep_kernel<<<32, 256, 0, stream>>>(pa);
    table_kernel<<<LL * 65, 256, 0, stream>>>(w1t, w2t, mlp_b1, mlp_b2, tab);

    // sort edges by dst (once; graph static across layers)
    hist_kernel<<<(EE + 255) / 256, 256, 0, stream>>>(edge_index, d_hist);
    scanA_kernel<<<SB, 256, 0, stream>>>(d_hist, d_bsum);
    scanB_kernel<<<1, 256, 0, stream>>>(d_bsum, d_done);
    scanC_kernel<<<SB, 256, 0, stream>>>(d_hist, d_bsum, d_rs, d_bcur);
    scat1_kernel<<<NBUK, 256, 0, stream>>>(edge_attr, edge_index, d_bcur, d_tmp8);
    scat2_kernel<<<NBUK, 256, 0, stream>>>(d_rs, d_tmp8, d_es);

    xf0_kernel<<<NBLK, 256, 0, stream>>>(x_atoms, embedding, c1t, hb, xfA);
    bf16* xf_in = xfA;
    bf16* xf_out = xfB;
    for (int l = 0; l < LL; l++) {
        edge_kernel<<<NN / 4, 256, 0, stream>>>(d_es, d_rs, d_hist, xf_in,
                                                tab + (size_t)l * (NK + 1) * FF, aggb);
        const bf16* c1n = (l + 1 < LL) ? (c1t + (size_t)(l + 1) * FF * HH) : nullptr;
        update_kernel<<<NBLK, 256, 0, stream>>>(aggb, c2t + (size_t)l * HH * FF,
                                                conv2_b + l * HH,
                                                ilt + (size_t)l * HH * HH, int_lin_b + l * HH,
                                                hb, c1n, xf_out,
                                                l1t, lin1_b, l2t, lin2_b, partial,
                                                readout_w, readout_b, (float*)d_out, d_done);
        bf16* tmp = xf_in; xf_in = xf_out; xf_out = tmp;
    }
}

// Round 15
// 621.332 us; speedup vs baseline: 1.4144x; 1.0112x over previous
//
#include <hip/hip_runtime.h>
#include <hip/hip_bf16.h>
#include <math.h>

#define NN 50000
#define EE 800000
#define HH 128
#define FF 128
#define GG 50
#define LL 6
#define H2D 64
#define OUT_DIM 12
#define NK 4096          // nearest-neighbor table intervals; knots 0..NK (4097)
#define NBLK 782         // ceil(NN/64)
#define SB 196           // scan blocks: ceil(NN/256)
#define NBUK 196         // scatter buckets: 256 nodes each

typedef __bf16 bf16;
typedef __attribute__((ext_vector_type(8))) __bf16 bf16x8;
typedef __attribute__((ext_vector_type(4))) __bf16 bf16x4;
typedef __attribute__((ext_vector_type(4))) float f32x4;
typedef __attribute__((ext_vector_type(4))) unsigned u32x4;

#define DEV __device__ __forceinline__

// fast shifted-softplus: hw v_exp/v_log, err ~1e-6 << bf16 rounding
DEV float sspf(float x) {
    return fmaxf(x, 0.f) + __logf(1.f + __expf(-fabsf(x))) - 0.69314718055994531f;
}

DEV f32x4 mfma16(bf16x8 a, bf16x8 b, f32x4 c) {
    return __builtin_amdgcn_mfma_f32_16x16x32_bf16(a, b, c, 0, 0, 0);
}

DEV float blo(unsigned u) { return __uint_as_float(u << 16); }
DEV float bhi(unsigned u) { return __uint_as_float(u & 0xffff0000u); }

// -------- prep: transpose all weights to [n][k] bf16 (+ zero hist) -----------
struct PrepArgs {
    const float *conv1_w, *conv2_w, *int_lin_w, *mlp_w1, *mlp_w2, *lin1_w, *lin2_w;
    bf16 *c1t, *c2t, *ilt, *w1t, *w2t, *l1t, *l2t;
    int* hist;
};

__global__ void prep_kernel(PrepArgs p) {
    int j = blockIdx.x;
    // fused hist zeroing (grid-stride over all 32 blocks)
    for (int i = blockIdx.x * 256 + threadIdx.x; i < NN; i += 32 * 256) p.hist[i] = 0;
    const float* src = nullptr; bf16* dst = nullptr; int R = 0, C = 0, K = 0;
    if (j < 30) {
        int l = j / 5, m = j % 5;
        switch (m) {
            case 0: src = p.conv1_w + l * HH * FF;   dst = p.c1t + l * FF * HH;  R = HH; C = FF; K = HH; break;
            case 1: src = p.conv2_w + l * FF * HH;   dst = p.c2t + l * HH * FF;  R = FF; C = HH; K = FF; break;
            case 2: src = p.int_lin_w + l * HH * HH; dst = p.ilt + l * HH * HH;  R = HH; C = HH; K = HH; break;
            case 3: src = p.mlp_w1 + l * GG * FF;    dst = p.w1t + l * FF * 64;  R = GG; C = FF; K = 64; break;
            case 4: src = p.mlp_w2 + l * FF * FF;    dst = p.w2t + l * FF * FF;  R = FF; C = FF; K = FF; break;
        }
    } else if (j == 30) { src = p.lin1_w; dst = p.l1t; R = HH;  C = H2D; K = HH; }
    else                { src = p.lin2_w; dst = p.l2t; R = H2D; C = H2D; K = H2D; }
    int total = C * K;
    for (int idx = threadIdx.x; idx < total; idx += blockDim.x) {
        int c = idx / K, r = idx - c * K;
        dst[idx] = (r < R) ? (bf16)src[r * C + c] : (bf16)0.f;
    }
}

// -------- table build via MFMA: T[l][r][:] = (ssp(g(d)@W1+b1)@W2+b2)*C(d) ----
__global__ __launch_bounds__(256) void table_kernel(const bf16* __restrict__ w1t,
                                                    const bf16* __restrict__ w2t,
                                                    const float* __restrict__ mlp_b1,
                                                    const float* __restrict__ mlp_b2,
                                                    bf16* __restrict__ tab) {
    __shared__ bf16 sW1[128 * 72];
    __shared__ bf16 sW2[128 * 136];
    __shared__ bf16 sT1[64 * 136];
    int tid = threadIdx.x;
    int l = blockIdx.x / 65, rb = blockIdx.x % 65;
    const bf16* W1 = w1t + (size_t)l * 128 * 64;
    const bf16* W2 = w2t + (size_t)l * 128 * 128;
    for (int idx = tid * 8; idx < 128 * 64; idx += 2048) {
        int n = idx >> 6, k = idx & 63;
        *(bf16x8*)&sW1[n * 72 + k] = *(const bf16x8*)(W1 + idx);
    }
    for (int idx = tid * 8; idx < 128 * 128; idx += 2048) {
        int n = idx >> 7, k = idx & 127;
        *(bf16x8*)&sW2[n * 136 + k] = *(const bf16x8*)(W2 + idx);
    }
    int w = tid >> 6, lane = tid & 63, ln = lane & 15, kg = lane >> 4;
    int rowt = rb * 64 + w * 16;
    float d1 = (float)min(rowt + ln, NK) * (10.f / NK);
    const float step = 10.f / 49.f;
    const float coeff = -0.5f / (step * step);
    __syncthreads();
    // GEMM1: in-register gaussian basis @ W1
    f32x4 acc[8] = {};
#pragma unroll
    for (int k0 = 0; k0 < 64; k0 += 32) {
        bf16x8 a;
#pragma unroll
        for (int jj = 0; jj < 8; jj++) {
            int g = k0 + kg * 8 + jj;
            float diff = d1 - g * step;
            float v = (g < GG) ? __expf(coeff * diff * diff) : 0.f;
            a[jj] = (bf16)v;
        }
#pragma unroll
        for (int t = 0; t < 8; t++) {
            bf16x8 b = *(const bf16x8*)&sW1[(t * 16 + ln) * 72 + k0 + kg * 8];
            acc[t] = mfma16(a, b, acc[t]);
        }
    }
    const float* b1 = mlp_b1 + l * FF;
#pragma unroll
    for (int t = 0; t < 8; t++) {
        int colt = t * 16 + ln;
        float bb = b1[colt];
#pragma unroll
        for (int r = 0; r < 4; r++)
            sT1[(w * 16 + kg * 4 + r) * 136 + colt] = (bf16)sspf(acc[t][r] + bb);
    }
    __syncthreads();
    f32x4 acc2[8] = {};
#pragma unroll
    for (int k0 = 0; k0 < 128; k0 += 32) {
        bf16x8 a = *(const bf16x8*)&sT1[(w * 16 + ln) * 136 + k0 + kg * 8];
#pragma unroll
        for (int t = 0; t < 8; t++) {
            bf16x8 b = *(const bf16x8*)&sW2[(t * 16 + ln) * 136 + k0 + kg * 8];
            acc2[t] = mfma16(a, b, acc2[t]);
        }
    }
    const float* b2 = mlp_b2 + l * FF;
    float Cw[4]; int rrow[4];
#pragma unroll
    for (int r = 0; r < 4; r++) {
        int rr = rowt + kg * 4 + r;
        rrow[r] = rr;
        float dd = (float)min(rr, NK) * (10.f / NK);
        Cw[r] = 0.5f * (cosf(dd * 0.31415926535897932f) + 1.f);
    }
#pragma unroll
    for (int t = 0; t < 8; t++) {
        int colt = t * 16 + ln;
        float bb = b2[colt];
#pragma unroll
        for (int r = 0; r < 4; r++) {
            if (rrow[r] <= NK)
                tab[((size_t)l * (NK + 1) + rrow[r]) * FF + colt] = (bf16)((acc2[t][r] + bb) * Cw[r]);
        }
    }
}

// -------- edge sort by dst: histogram / hierarchical scan --------------------
__global__ void hist_kernel(const int* __restrict__ eidx, int* __restrict__ hist) {
    int e = blockIdx.x * 256 + threadIdx.x;
    if (e < EE) atomicAdd(&hist[eidx[EE + e]], 1);
}

__global__ __launch_bounds__(256) void scanA_kernel(const int* __restrict__ hist,
                                                    int* __restrict__ bsum) {
    __shared__ int red[256];
    int t = threadIdx.x;
    int i = blockIdx.x * 256 + t;
    int v = (i < NN) ? hist[i] : 0;
    red[t] = v;
    __syncthreads();
    for (int off = 128; off > 0; off >>= 1) {
        if (t < off) red[t] += red[t + off];
        __syncthreads();
    }
    if (t == 0) bsum[blockIdx.x] = red[0];
}

__global__ __launch_bounds__(256) void scanB_kernel(int* __restrict__ bsum) {
    __shared__ int buf[256];
    int t = threadIdx.x;
    int v = (t < SB) ? bsum[t] : 0;
    buf[t] = v;
    __syncthreads();
    for (int off = 1; off < 256; off <<= 1) {
        int y = (t >= off) ? buf[t - off] : 0;
        __syncthreads();
        buf[t] += y;
        __syncthreads();
    }
    if (t < SB) bsum[t] = buf[t] - v;   // exclusive
}

__global__ __launch_bounds__(256) void scanC_kernel(const int* __restrict__ hist,
                                                    const int* __restrict__ bsum,
                                                    int* __restrict__ rs,
                                                    int* __restrict__ bucket_cur) {
    __shared__ int buf[256];
    int t = threadIdx.x;
    int i = blockIdx.x * 256 + t;
    int v = (i < NN) ? hist[i] : 0;
    buf[t] = v;
    __syncthreads();
    for (int off = 1; off < 256; off <<= 1) {
        int y = (t >= off) ? buf[t - off] : 0;
        __syncthreads();
        buf[t] += y;
        __syncthreads();
    }
    if (i < NN) {
        int ex = buf[t] - v + bsum[blockIdx.x];
        rs[i] = ex;
        if ((i & 255) == 0) bucket_cur[i >> 8] = ex;   // bucket base (fused bukinit)
    }
}

// -------- bucketed two-pass scatter (kills 64B-line write amplification) -----
// pass 1: 196 blocks x 4096 edges -> bucket-grouped tmp (int2: packed, dst)
__global__ __launch_bounds__(256) void scat1_kernel(const float* __restrict__ eattr,
                                                    const int* __restrict__ eidx,
                                                    int* __restrict__ bucket_cur,
                                                    int2* __restrict__ tmp8) {
    __shared__ int cnt[NBUK];
    __shared__ int res[NBUK];
    int t = threadIdx.x;
    for (int i = t; i < NBUK; i += 256) cnt[i] = 0;
    __syncthreads();
    int e0 = blockIdx.x * 4096;
    int pv[16], dd[16], bk[16];
#pragma unroll
    for (int i = 0; i < 16; i++) {
        int e = e0 + i * 256 + t;
        if (e < EE) {
            int d = eidx[EE + e];
            int k = (int)(eattr[e] * ((float)NK / 10.f) + 0.5f);
            k = min(k, NK);
            pv[i] = k | (eidx[e] << 13);
            dd[i] = d;
            bk[i] = d >> 8;
            atomicAdd(&cnt[bk[i]], 1);
        } else bk[i] = -1;
    }
    __syncthreads();
    for (int i = t; i < NBUK; i += 256) {
        int c = cnt[i];
        res[i] = (c > 0) ? atomicAdd(&bucket_cur[i], c) : 0;
        cnt[i] = 0;          // reuse as local rank counter
    }
    __syncthreads();
#pragma unroll
    for (int i = 0; i < 16; i++) {
        if (bk[i] >= 0) {
            int rank = atomicAdd(&cnt[bk[i]], 1);
            int2 v; v.x = pv[i]; v.y = dd[i];
            tmp8[res[bk[i]] + rank] = v;
        }
    }
}

// pass 2: one block per bucket -> final dst-sorted es (dense 16KB window)
__global__ __launch_bounds__(256) void scat2_kernel(const int* __restrict__ rs,
                                                    const int2* __restrict__ tmp8,
                                                    int* __restrict__ es) {
    __shared__ int off[256];
    __shared__ int loc[256];
    int b = blockIdx.x, t = threadIdx.x;
    int nb0 = b * 256;
    int nnb = min(256, NN - nb0);          // nodes in this bucket
    int base = rs[nb0];
    int end = (nb0 + 256 < NN) ? rs[nb0 + 256] : EE;
    loc[t] = 0;
    if (t < nnb) off[t] = rs[nb0 + t] - base;
    __syncthreads();
    for (int e = base + t; e < end; e += 256) {
        int2 v = tmp8[e];
        int nl = v.y - nb0;
        int rank = atomicAdd(&loc[nl], 1);
        es[base + off[nl] + rank] = v.x;
    }
}

// -------- xf0: hb = embedding[x_atoms]; xf = hb @ conv1_w (fused, layer 0) ---
__global__ __launch_bounds__(256) void xf0_kernel(const int* __restrict__ x_atoms,
                                                  const float* __restrict__ emb,
                                                  const bf16* __restrict__ c1t,
                                                  bf16* __restrict__ hb,
                                                  bf16* __restrict__ xf) {
    __shared__ bf16 sB[128 * 136];
    int tid = threadIdx.x;
    for (int idx = tid * 8; idx < 128 * 128; idx += 2048) {
        int n = idx >> 7, k = idx & 127;
        *(bf16x8*)&sB[n * 136 + k] = *(const bf16x8*)(c1t + idx);
    }
    int w = tid >> 6, lane = tid & 63, ln = lane & 15, kg = lane >> 4;
    int rowt = blockIdx.x * 64 + w * 16;
    int nrow = rowt + ln;
    int arow = min(nrow, NN - 1);
    bool rowok = nrow < NN;
    int atom = x_atoms[arow];
    __syncthreads();
    f32x4 acc[8] = {};
#pragma unroll
    for (int k0 = 0; k0 < 128; k0 += 32) {
        const float* ep = emb + (size_t)atom * HH + k0 + kg * 8;
        f32x4 u0 = *(const f32x4*)ep;
        f32x4 u1 = *(const f32x4*)(ep + 4);
        bf16x8 a;
#pragma unroll
        for (int q = 0; q < 4; q++) { a[q] = (bf16)u0[q]; a[q + 4] = (bf16)u1[q]; }
        if (rowok) *(bf16x8*)(hb + (size_t)nrow * HH + k0 + kg * 8) = a;
#pragma unroll
        for (int t = 0; t < 8; t++) {
            bf16x8 b = *(const bf16x8*)&sB[(t * 16 + ln) * 136 + k0 + kg * 8];
            acc[t] = mfma16(a, b, acc[t]);
        }
    }
#pragma unroll
    for (int t = 0; t < 8; t++) {
        int colt = t * 16 + ln;
#pragma unroll
        for (int r = 0; r < 4; r++) {
            int orow = rowt + kg * 4 + r;
            if (orow < NN) xf[orow * FF + colt] = (bf16)acc[t][r];
        }
    }
}

// -------- edge kernel: CSR, one wave/node, nearest-knot, 4 edges/iter --------
__global__ __launch_bounds__(256) void edge_kernel(const int* __restrict__ es,
                                                   const int* __restrict__ rs,
                                                   const int* __restrict__ hist,
                                                   const bf16* __restrict__ xf,
                                                   const bf16* __restrict__ tab,
                                                   bf16* __restrict__ aggb) {
    int tid = threadIdx.x;
    int w = tid >> 6, lane = tid & 63;
    int q = lane >> 4, cl = lane & 15;      // quarter q handles edge 4j+q; lane covers ch [8cl,8cl+8)
    int n = blockIdx.x * 4 + w;
    int start = rs[n], deg = hist[n];
    float a0 = 0.f, a1 = 0.f, a2 = 0.f, a3 = 0.f;
    float a4 = 0.f, a5 = 0.f, a6 = 0.f, a7 = 0.f;
    for (int base = 0; base < deg; base += 64) {
        int cnt = min(deg - base, 64);
        int pv = (lane < cnt) ? es[start + base + lane] : 0;
        int iters = (cnt + 3) >> 2;
#pragma unroll 4
        for (int j = 0; j < iters; j++) {
            int jj = 4 * j + q;
            bool valid = jj < cnt;
            int v = __shfl(pv, jj);
            int k = v & 8191;
            int s = v >> 13;
            u32x4 tp = *(const u32x4*)(tab + (size_t)k * FF + 8 * cl);
            u32x4 xu = *(const u32x4*)(xf + (size_t)s * FF + 8 * cl);
            unsigned t0 = valid ? tp.x : 0u;
            unsigned t1 = valid ? tp.y : 0u;
            unsigned t2 = valid ? tp.z : 0u;
            unsigned t3 = valid ? tp.w : 0u;
            a0 = fmaf(blo(t0), blo(xu.x), a0);
            a1 = fmaf(bhi(t0), bhi(xu.x), a1);
            a2 = fmaf(blo(t1), blo(xu.y), a2);
            a3 = fmaf(bhi(t1), bhi(xu.y), a3);
            a4 = fmaf(blo(t2), blo(xu.z), a4);
            a5 = fmaf(bhi(t2), bhi(xu.z), a5);
            a6 = fmaf(blo(t3), blo(xu.w), a6);
            a7 = fmaf(bhi(t3), bhi(xu.w), a7);
        }
    }
    a0 += __shfl_xor(a0, 16); a0 += __shfl_xor(a0, 32);
    a1 += __shfl_xor(a1, 16); a1 += __shfl_xor(a1, 32);
    a2 += __shfl_xor(a2, 16); a2 += __shfl_xor(a2, 32);
    a3 += __shfl_xor(a3, 16); a3 += __shfl_xor(a3, 32);
    a4 += __shfl_xor(a4, 16); a4 += __shfl_xor(a4, 32);
    a5 += __shfl_xor(a5, 16); a5 += __shfl_xor(a5, 32);
    a6 += __shfl_xor(a6, 16); a6 += __shfl_xor(a6, 32);
    a7 += __shfl_xor(a7, 16); a7 += __shfl_xor(a7, 32);
    if (q == 0) {
        bf16x8 pk;
        pk[0] = (bf16)a0; pk[1] = (bf16)a1; pk[2] = (bf16)a2; pk[3] = (bf16)a3;
        pk[4] = (bf16)a4; pk[5] = (bf16)a5; pk[6] = (bf16)a6; pk[7] = (bf16)a7;
        *(bf16x8*)(aggb + (size_t)n * FF + 8 * cl) = pk;
    }
}

// -------- update: transposed-output GEMMs (thread = 1 node x 4-feat spans) ---
__global__ __launch_bounds__(256) void update_kernel(const bf16* __restrict__ aggb,
                                                     const bf16* __restrict__ c2t,
                                                     const float* __restrict__ c2b,
                                                     const bf16* __restrict__ ilt,
                                                     const float* __restrict__ ilb,
                                                     bf16* __restrict__ hb,
                                                     const bf16* __restrict__ c1n,
                                                     bf16* __restrict__ xf_out,
                                                     const bf16* __restrict__ l1t,
                                                     const float* __restrict__ l1b,
                                                     const bf16* __restrict__ l2t,
                                                     const float* __restrict__ l2b,
                                                     float* __restrict__ partial) {
    __shared__ bf16 sB[128 * 136];   // restaged per GEMM
    __shared__ bf16 sT[64 * 136];
    int tid = threadIdx.x;
    int w = tid >> 6, lane = tid & 63, ln = lane & 15, kg = lane >> 4;
    int rowt = blockIdx.x * 64 + w * 16;
    int nrow = rowt + ln;                 // this thread's node (transposed layout)
    int arow = min(nrow, NN - 1);
    bool rowok = nrow < NN;
    // prefetch residual h: node nrow, feats t*16+kg*4 .. +4
    bf16x4 hpre[8];
#pragma unroll
    for (int t = 0; t < 8; t++)
        hpre[t] = *(const bf16x4*)(hb + (size_t)arow * HH + t * 16 + kg * 4);
    for (int idx = tid * 8; idx < 128 * 128; idx += 2048) {
        int n = idx >> 7, k = idx & 127;
        *(bf16x8*)&sB[n * 136 + k] = *(const bf16x8*)(c2t + idx);
    }
    __syncthreads();
    // GEMM1 (Ct): out[feat][node] = conv2^T @ agg^T  (operand-swapped MFMA)
    f32x4 acc[8] = {};
#pragma unroll
    for (int k0 = 0; k0 < 128; k0 += 32) {
        bf16x8 bfrag = *(const bf16x8*)(aggb + (size_t)arow * FF + k0 + kg * 8);
#pragma unroll
        for (int t = 0; t < 8; t++) {
            bf16x8 afrag = *(const bf16x8*)&sB[(t * 16 + ln) * 136 + k0 + kg * 8];
            acc[t] = mfma16(afrag, bfrag, acc[t]);
        }
    }
    // epilogue1: thread holds feats t*16+kg*4+[0..4) of node nrow -> b64 LDS writes
#pragma unroll
    for (int t = 0; t < 8; t++) {
        f32x4 bb = *(const f32x4*)(c2b + t * 16 + kg * 4);
        bf16x4 pk;
#pragma unroll
        for (int r = 0; r < 4; r++) pk[r] = (bf16)sspf(acc[t][r] + bb[r]);
        *(bf16x4*)&sT[(w * 16 + ln) * 136 + t * 16 + kg * 4] = pk;
    }
    __syncthreads();
    for (int idx = tid * 8; idx < 128 * 128; idx += 2048) {
        int n = idx >> 7, k = idx & 127;
        *(bf16x8*)&sB[n * 136 + k] = *(const bf16x8*)(ilt + idx);
    }
    __syncthreads();
    f32x4 acc2[8] = {};
#pragma unroll
    for (int k0 = 0; k0 < 128; k0 += 32) {
        bf16x8 bfrag = *(const bf16x8*)&sT[(w * 16 + ln) * 136 + k0 + kg * 8];
#pragma unroll
        for (int t = 0; t < 8; t++) {
            bf16x8 afrag = *(const bf16x8*)&sB[(t * 16 + ln) * 136 + k0 + kg * 8];
            acc2[t] = mfma16(afrag, bfrag, acc2[t]);
        }
    }
    bool is_last = (c1n == nullptr);
    // epilogue2: residual add, vector stores (own sT rows only -> no barrier needed)
#pragma unroll
    for (int t = 0; t < 8; t++) {
        f32x4 bb = *(const f32x4*)(ilb + t * 16 + kg * 4);
        bf16x4 pk;
#pragma unroll
        for (int r = 0; r < 4; r++)
            pk[r] = (bf16)((float)hpre[t][r] + acc2[t][r] + bb[r]);
        if (rowok && !is_last) *(bf16x4*)(hb + (size_t)nrow * HH + t * 16 + kg * 4) = pk;
        *(bf16x4*)&sT[(w * 16 + ln) * 136 + t * 16 + kg * 4] = pk;
    }
    if (!is_last) {
        // fused next-layer xf = h_new @ conv1_next (same transposed form)
        __syncthreads();
        for (int idx = tid * 8; idx < 128 * 128; idx += 2048) {
            int n = idx >> 7, k = idx & 127;
            *(bf16x8*)&sB[n * 136 + k] = *(const bf16x8*)(c1n + idx);
        }
        __syncthreads();
        f32x4 acc3[8] = {};
#pragma unroll
        for (int k0 = 0; k0 < 128; k0 += 32) {
            bf16x8 bfrag = *(const bf16x8*)&sT[(w * 16 + ln) * 136 + k0 + kg * 8];
#pragma unroll
            for (int t = 0; t < 8; t++) {
                bf16x8 afrag = *(const bf16x8*)&sB[(t * 16 + ln) * 136 + k0 + kg * 8];
                acc3[t] = mfma16(afrag, bfrag, acc3[t]);
            }
        }
#pragma unroll
        for (int t = 0; t < 8; t++) {
            bf16x4 pk;
#pragma unroll
            for (int r = 0; r < 4; r++) pk[r] = (bf16)acc3[t][r];
            if (rowok) *(bf16x4*)(xf_out + (size_t)nrow * FF + t * 16 + kg * 4) = pk;
        }
    } else {
        // fused head: ssp(h@lin1+b)@lin2+b, per-block partial sum (runs once)
        __syncthreads();
        for (int idx = tid * 8; idx < 64 * 128; idx += 2048) {
            int n = idx >> 7, k = idx & 127;
            *(bf16x8*)&sB[n * 136 + k] = *(const bf16x8*)(l1t + idx);
        }
        __syncthreads();
        f32x4 acch[4] = {};
#pragma unroll
        for (int k0 = 0; k0 < 128; k0 += 32) {
            bf16x8 a = *(const bf16x8*)&sT[(w * 16 + ln) * 136 + k0 + kg * 8];
#pragma unroll
            for (int t = 0; t < 4; t++) {
                bf16x8 b = *(const bf16x8*)&sB[(t * 16 + ln) * 136 + k0 + kg * 8];
                acch[t] = mfma16(a, b, acch[t]);
            }
        }
#pragma unroll
        for (int t = 0; t < 4; t++) {
            int colt = t * 16 + ln;
            float bb = l1b[colt];
#pragma unroll
            for (int r = 0; r < 4; r++)
                sT[(w * 16 + kg * 4 + r) * 136 + colt] = (bf16)sspf(acch[t][r] + bb);
        }
        __syncthreads();
        for (int idx = tid * 8; idx < 64 * 64; idx += 2048) {
            int n = idx >> 6, k = idx & 63;
            *(bf16x8*)&sB[n * 136 + k] = *(const bf16x8*)(l2t + idx);
        }
        __syncthreads();
        f32x4 acc2h[4] = {};
#pragma unroll
        for (int k0 = 0; k0 < 64; k0 += 32) {
            bf16x8 a = *(const bf16x8*)&sT[(w * 16 + ln) * 136 + k0 + kg * 8];
#pragma unroll
            for (int t = 0; t < 4; t++) {
                bf16x8 b = *(const bf16x8*)&sB[(t * 16 + ln) * 136 + k0 + kg * 8];
                acc2h[t] = mfma16(a, b, acc2h[t]);
            }
        }
        __syncthreads();   // all sT reads done; reuse as f32 scratch
        float* sPart = (float*)sT;
#pragma unroll
        for (int t = 0; t < 4; t++) {
            int colt = t * 16 + ln;
            float bb = l2b[colt];
            float v = 0.f;
#pragma unroll
            for (int r = 0; r < 4; r++) {
                int orow = rowt + kg * 4 + r;
                if (orow < NN) v += acc2h[t][r] + bb;
            }
            v += __shfl_xor(v, 16);
            v += __shfl_xor(v, 32);
            if (kg == 0) sPart[w * 64 + colt] = v;
        }
        __syncthreads();
        if (tid < 64) {
            float s = sPart[tid] + sPart[64 + tid] + sPart[128 + tid] + sPart[192 + tid];
            partial[blockIdx.x * 64 + tid] = s;
        }
    }
}

// -------- final: 4 threads per column over 782 partial blocks ---------------
__global__ __launch_bounds__(256) void final_kernel(const float* __restrict__ partial,
                                                    const float* __restrict__ rw,
                                                    const float* __restrict__ rb,
                                                    float* __restrict__ out) {
    __shared__ float sv[256];
    int t = threadIdx.x;
    int col = t & 63, seg = t >> 6;          // 4 segments of ~196 blocks
    int b0 = seg * 196, b1 = min(b0 + 196, NBLK);
    float s = 0.f;
    for (int b = b0; b < b1; b++) s += partial[b * 64 + col];
    sv[seg * 64 + col] = s;
    __syncthreads();
    if (t < 64) sv[t] = sv[t] + sv[64 + t] + sv[128 + t] + sv[192 + t];
    __syncthreads();
    if (t < OUT_DIM) {
        float o = rb[t];
        for (int i = 0; i < H2D; i++) o += sv[i] * rw[i * OUT_DIM + t];
        out[t] = o;
    }
}

// -------- launch -------------------------------------------------------------
extern "C" void kernel_launch(void* const* d_in, const int* in_sizes, int n_in,
                              void* d_out, int out_size, void* d_ws, size_t ws_size,
                              hipStream_t stream) {
    const int*   x_atoms    = (const int*)d_in[0];
    const int*   edge_index = (const int*)d_in[1];
    const float* edge_attr  = (const float*)d_in[2];
    const float* embedding  = (const float*)d_in[3];
    const float* mlp_w1     = (const float*)d_in[4];
    const float* mlp_b1     = (const float*)d_in[5];
    const float* mlp_w2     = (const float*)d_in[6];
    const float* mlp_b2     = (const float*)d_in[7];
    const float* conv1_w    = (const float*)d_in[8];
    const float* conv2_w    = (const float*)d_in[9];
    const float* conv2_b    = (const float*)d_in[10];
    const float* int_lin_w  = (const float*)d_in[11];
    const float* int_lin_b  = (const float*)d_in[12];
    const float* lin1_w     = (const float*)d_in[13];
    const float* lin1_b     = (const float*)d_in[14];
    const float* lin2_w     = (const float*)d_in[15];
    const float* lin2_b     = (const float*)d_in[16];
    const float* readout_w  = (const float*)d_in[17];
    const float* readout_b  = (const float*)d_in[18];

    char* ws = (char*)d_ws;
    bf16*  hb      = (bf16*)(ws + 0);              // 12,800,000
    bf16*  xfA     = (bf16*)(ws + 12800000);       // 12,800,000
    bf16*  xfB     = (bf16*)(ws + 25600000);       // 12,800,000
    bf16*  aggb    = (bf16*)(ws + 38400000);       // 12,800,000
    float* partial = (float*)(ws + 51200000);      // 200,192
    size_t wb = 51400192;
    bf16* c1t = (bf16*)(ws + wb);                  // 196,608
    bf16* c2t = (bf16*)(ws + wb + 196608);
    bf16* ilt = (bf16*)(ws + wb + 393216);
    bf16* w1t = (bf16*)(ws + wb + 589824);         // 98,304
    bf16* w2t = (bf16*)(ws + wb + 688128);         // 196,608
    bf16* l1t = (bf16*)(ws + wb + 884736);         // 16,384
    bf16* l2t = (bf16*)(ws + wb + 901120);         // 8,192 -> ends 52,309,504
    int*   d_hist = (int*)(ws + 52309504);         // 200,000
    int*   d_rs   = (int*)(ws + 52509504);         // 200,000
    int*   d_bcur = (int*)(ws + 52709504);         // 1,024 (bucket_cur)
    int*   d_bsum = (int*)(ws + 52710528);         // 1,024
    int*   d_es   = (int*)(ws + 52711552);         // 3,200,000 -> 55,911,552
    bf16*  tab    = (bf16*)(ws + 55911552);        // 6*4097*128*2 = 6,292,992 -> 62,204,544
    int2*  d_tmp8 = (int2*)(ws + 62204544);        // 6,400,000 -> 68,604,544

    PrepArgs pa = { conv1_w, conv2_w, int_lin_w, mlp_w1, mlp_w2, lin1_w, lin2_w,
                    c1t, c2t, ilt, w1t, w2t, l1t, l2t, d_hist };
    prep_kernel<<<32, 256, 0, stream>>>(pa);
    table_kernel<<<LL * 65, 256, 0, stream>>>(w1t, w2t, mlp_b1, mlp_b2, tab);

    // sort edges by dst (once; graph static across layers)
    hist_kernel<<<(EE + 255) / 256, 256, 0, stream>>>(edge_index, d_hist);
    scanA_kernel<<<SB, 256, 0, stream>>>(d_hist, d_bsum);
    scanB_kernel<<<1, 256, 0, stream>>>(d_bsum);
    scanC_kernel<<<SB, 256, 0, stream>>>(d_hist, d_bsum, d_rs, d_bcur);
    scat1_kernel<<<NBUK, 256, 0, stream>>>(edge_attr, edge_index, d_bcur, d_tmp8);
    scat2_kernel<<<NBUK, 256, 0, stream>>>(d_rs, d_tmp8, d_es);

    xf0_kernel<<<NBLK, 256, 0, stream>>>(x_atoms, embedding, c1t, hb, xfA);
    bf16* xf_in = xfA;
    bf16* xf_out = xfB;
    for (int l = 0; l < LL; l++) {
        edge_kernel<<<NN / 4, 256, 0, stream>>>(d_es, d_rs, d_hist, xf_in,
                                                tab + (size_t)l * (NK + 1) * FF, aggb);
        const bf16* c1n = (l + 1 < LL) ? (c1t + (size_t)(l + 1) * FF * HH) : nullptr;
        update_kernel<<<NBLK, 256, 0, stream>>>(aggb, c2t + (size_t)l * HH * FF,
                                                conv2_b + l * HH,
                                                ilt + (size_t)l * HH * HH, int_lin_b + l * HH,
                                                hb, c1n, xf_out,
                                                l1t, lin1_b, l2t, lin2_b, partial);
        bf16* tmp = xf_in; xf_in = xf_out; xf_out = tmp;
    }
    final_kernel<<<1, 256, 0, stream>>>(partial, readout_w, readout_b, (float*)d_out);
}

// Round 16
// 571.311 us; speedup vs baseline: 1.5382x; 1.0876x over previous
//
#include <hip/hip_runtime.h>
#include <hip/hip_bf16.h>
#include <math.h>

#define NN 50000
#define EE 800000
#define HH 128
#define FF 128
#define GG 50
#define LL 6
#define H2D 64
#define OUT_DIM 12
#define NK 4096          // nearest-neighbor table intervals; knots 0..NK (4097)
#define NBLK 782         // ceil(NN/64)
#define SB 196           // scan blocks: ceil(NN/256)
#define NBUK 196         // scatter buckets: 256 nodes each

typedef __bf16 bf16;
typedef __attribute__((ext_vector_type(8))) __bf16 bf16x8;
typedef __attribute__((ext_vector_type(4))) __bf16 bf16x4;
typedef __attribute__((ext_vector_type(4))) float f32x4;
typedef __attribute__((ext_vector_type(4))) unsigned u32x4;

#define DEV __device__ __forceinline__

// fast shifted-softplus: hw v_exp/v_log, err ~1e-6 << bf16 rounding
DEV float sspf(float x) {
    return fmaxf(x, 0.f) + __logf(1.f + __expf(-fabsf(x))) - 0.69314718055994531f;
}

DEV f32x4 mfma16(bf16x8 a, bf16x8 b, f32x4 c) {
    return __builtin_amdgcn_mfma_f32_16x16x32_bf16(a, b, c, 0, 0, 0);
}

DEV float blo(unsigned u) { return __uint_as_float(u << 16); }
DEV float bhi(unsigned u) { return __uint_as_float(u & 0xffff0000u); }

// -------- prep: transpose all weights to [n][k] bf16 (+ zero hist) -----------
struct PrepArgs {
    const float *conv1_w, *conv2_w, *int_lin_w, *mlp_w1, *mlp_w2, *lin1_w, *lin2_w;
    bf16 *c1t, *c2t, *ilt, *w1t, *w2t, *l1t, *l2t;
    int* hist;
};

__global__ void prep_kernel(PrepArgs p) {
    int j = blockIdx.x;
    // fused hist zeroing (grid-stride over all 32 blocks)
    for (int i = blockIdx.x * 256 + threadIdx.x; i < NN; i += 32 * 256) p.hist[i] = 0;
    const float* src = nullptr; bf16* dst = nullptr; int R = 0, C = 0, K = 0;
    if (j < 30) {
        int l = j / 5, m = j % 5;
        switch (m) {
            case 0: src = p.conv1_w + l * HH * FF;   dst = p.c1t + l * FF * HH;  R = HH; C = FF; K = HH; break;
            case 1: src = p.conv2_w + l * FF * HH;   dst = p.c2t + l * HH * FF;  R = FF; C = HH; K = FF; break;
            case 2: src = p.int_lin_w + l * HH * HH; dst = p.ilt + l * HH * HH;  R = HH; C = HH; K = HH; break;
            case 3: src = p.mlp_w1 + l * GG * FF;    dst = p.w1t + l * FF * 64;  R = GG; C = FF; K = 64; break;
            case 4: src = p.mlp_w2 + l * FF * FF;    dst = p.w2t + l * FF * FF;  R = FF; C = FF; K = FF; break;
        }
    } else if (j == 30) { src = p.lin1_w; dst = p.l1t; R = HH;  C = H2D; K = HH; }
    else                { src = p.lin2_w; dst = p.l2t; R = H2D; C = H2D; K = H2D; }
    int total = C * K;
    for (int idx = threadIdx.x; idx < total; idx += blockDim.x) {
        int c = idx / K, r = idx - c * K;
        dst[idx] = (r < R) ? (bf16)src[r * C + c] : (bf16)0.f;
    }
}

// -------- table build via MFMA: T[l][r][:] = (ssp(g(d)@W1+b1)@W2+b2)*C(d) ----
__global__ __launch_bounds__(256) void table_kernel(const bf16* __restrict__ w1t,
                                                    const bf16* __restrict__ w2t,
                                                    const float* __restrict__ mlp_b1,
                                                    const float* __restrict__ mlp_b2,
                                                    bf16* __restrict__ tab) {
    __shared__ bf16 sW1[128 * 72];
    __shared__ bf16 sW2[128 * 136];
    __shared__ bf16 sT1[64 * 136];
    int tid = threadIdx.x;
    int l = blockIdx.x / 65, rb = blockIdx.x % 65;
    const bf16* W1 = w1t + (size_t)l * 128 * 64;
    const bf16* W2 = w2t + (size_t)l * 128 * 128;
    for (int idx = tid * 8; idx < 128 * 64; idx += 2048) {
        int n = idx >> 6, k = idx & 63;
        *(bf16x8*)&sW1[n * 72 + k] = *(const bf16x8*)(W1 + idx);
    }
    for (int idx = tid * 8; idx < 128 * 128; idx += 2048) {
        int n = idx >> 7, k = idx & 127;
        *(bf16x8*)&sW2[n * 136 + k] = *(const bf16x8*)(W2 + idx);
    }
    int w = tid >> 6, lane = tid & 63, ln = lane & 15, kg = lane >> 4;
    int rowt = rb * 64 + w * 16;
    float d1 = (float)min(rowt + ln, NK) * (10.f / NK);
    const float step = 10.f / 49.f;
    const float coeff = -0.5f / (step * step);
    __syncthreads();
    // GEMM1: in-register gaussian basis @ W1
    f32x4 acc[8] = {};
#pragma unroll
    for (int k0 = 0; k0 < 64; k0 += 32) {
        bf16x8 a;
#pragma unroll
        for (int jj = 0; jj < 8; jj++) {
            int g = k0 + kg * 8 + jj;
            float diff = d1 - g * step;
            float v = (g < GG) ? __expf(coeff * diff * diff) : 0.f;
            a[jj] = (bf16)v;
        }
#pragma unroll
        for (int t = 0; t < 8; t++) {
            bf16x8 b = *(const bf16x8*)&sW1[(t * 16 + ln) * 72 + k0 + kg * 8];
            acc[t] = mfma16(a, b, acc[t]);
        }
    }
    const float* b1 = mlp_b1 + l * FF;
#pragma unroll
    for (int t = 0; t < 8; t++) {
        int colt = t * 16 + ln;
        float bb = b1[colt];
#pragma unroll
        for (int r = 0; r < 4; r++)
            sT1[(w * 16 + kg * 4 + r) * 136 + colt] = (bf16)sspf(acc[t][r] + bb);
    }
    __syncthreads();
    f32x4 acc2[8] = {};
#pragma unroll
    for (int k0 = 0; k0 < 128; k0 += 32) {
        bf16x8 a = *(const bf16x8*)&sT1[(w * 16 + ln) * 136 + k0 + kg * 8];
#pragma unroll
        for (int t = 0; t < 8; t++) {
            bf16x8 b = *(const bf16x8*)&sW2[(t * 16 + ln) * 136 + k0 + kg * 8];
            acc2[t] = mfma16(a, b, acc2[t]);
        }
    }
    const float* b2 = mlp_b2 + l * FF;
    float Cw[4]; int rrow[4];
#pragma unroll
    for (int r = 0; r < 4; r++) {
        int rr = rowt + kg * 4 + r;
        rrow[r] = rr;
        float dd = (float)min(rr, NK) * (10.f / NK);
        Cw[r] = 0.5f * (cosf(dd * 0.31415926535897932f) + 1.f);
    }
#pragma unroll
    for (int t = 0; t < 8; t++) {
        int colt = t * 16 + ln;
        float bb = b2[colt];
#pragma unroll
        for (int r = 0; r < 4; r++) {
            if (rrow[r] <= NK)
                tab[((size_t)l * (NK + 1) + rrow[r]) * FF + colt] = (bf16)((acc2[t][r] + bb) * Cw[r]);
        }
    }
}

// -------- edge sort by dst: histogram / hierarchical scan --------------------
__global__ void hist_kernel(const int* __restrict__ eidx, int* __restrict__ hist) {
    int e = blockIdx.x * 256 + threadIdx.x;
    if (e < EE) atomicAdd(&hist[eidx[EE + e]], 1);
}

__global__ __launch_bounds__(256) void scanA_kernel(const int* __restrict__ hist,
                                                    int* __restrict__ bsum) {
    __shared__ int red[256];
    int t = threadIdx.x;
    int i = blockIdx.x * 256 + t;
    int v = (i < NN) ? hist[i] : 0;
    red[t] = v;
    __syncthreads();
    for (int off = 128; off > 0; off >>= 1) {
        if (t < off) red[t] += red[t + off];
        __syncthreads();
    }
    if (t == 0) bsum[blockIdx.x] = red[0];
}

__global__ __launch_bounds__(256) void scanB_kernel(int* __restrict__ bsum) {
    __shared__ int buf[256];
    int t = threadIdx.x;
    int v = (t < SB) ? bsum[t] : 0;
    buf[t] = v;
    __syncthreads();
    for (int off = 1; off < 256; off <<= 1) {
        int y = (t >= off) ? buf[t - off] : 0;
        __syncthreads();
        buf[t] += y;
        __syncthreads();
    }
    if (t < SB) bsum[t] = buf[t] - v;   // exclusive
}

__global__ __launch_bounds__(256) void scanC_kernel(const int* __restrict__ hist,
                                                    const int* __restrict__ bsum,
                                                    int* __restrict__ rs,
                                                    int* __restrict__ bucket_cur) {
    __shared__ int buf[256];
    int t = threadIdx.x;
    int i = blockIdx.x * 256 + t;
    int v = (i < NN) ? hist[i] : 0;
    buf[t] = v;
    __syncthreads();
    for (int off = 1; off < 256; off <<= 1) {
        int y = (t >= off) ? buf[t - off] : 0;
        __syncthreads();
        buf[t] += y;
        __syncthreads();
    }
    if (i < NN) {
        int ex = buf[t] - v + bsum[blockIdx.x];
        rs[i] = ex;
        if ((i & 255) == 0) bucket_cur[i >> 8] = ex;   // bucket base (fused bukinit)
    }
}

// -------- bucketed two-pass scatter (kills 64B-line write amplification) -----
// pass 1: 196 blocks x 4096 edges -> bucket-grouped tmp (int2: packed, dst)
__global__ __launch_bounds__(256) void scat1_kernel(const float* __restrict__ eattr,
                                                    const int* __restrict__ eidx,
                                                    int* __restrict__ bucket_cur,
                                                    int2* __restrict__ tmp8) {
    __shared__ int cnt[NBUK];
    __shared__ int res[NBUK];
    int t = threadIdx.x;
    for (int i = t; i < NBUK; i += 256) cnt[i] = 0;
    __syncthreads();
    int e0 = blockIdx.x * 4096;
    int pv[16], dd[16], bk[16];
#pragma unroll
    for (int i = 0; i < 16; i++) {
        int e = e0 + i * 256 + t;
        if (e < EE) {
            int d = eidx[EE + e];
            int k = (int)(eattr[e] * ((float)NK / 10.f) + 0.5f);
            k = min(k, NK);
            pv[i] = k | (eidx[e] << 13);
            dd[i] = d;
            bk[i] = d >> 8;
            atomicAdd(&cnt[bk[i]], 1);
        } else bk[i] = -1;
    }
    __syncthreads();
    for (int i = t; i < NBUK; i += 256) {
        int c = cnt[i];
        res[i] = (c > 0) ? atomicAdd(&bucket_cur[i], c) : 0;
        cnt[i] = 0;          // reuse as local rank counter
    }
    __syncthreads();
#pragma unroll
    for (int i = 0; i < 16; i++) {
        if (bk[i] >= 0) {
            int rank = atomicAdd(&cnt[bk[i]], 1);
            int2 v; v.x = pv[i]; v.y = dd[i];
            tmp8[res[bk[i]] + rank] = v;
        }
    }
}

// pass 2: one block per bucket -> final dst-sorted es (dense 16KB window)
__global__ __launch_bounds__(256) void scat2_kernel(const int* __restrict__ rs,
                                                    const int2* __restrict__ tmp8,
                                                    int* __restrict__ es) {
    __shared__ int off[256];
    __shared__ int loc[256];
    int b = blockIdx.x, t = threadIdx.x;
    int nb0 = b * 256;
    int nnb = min(256, NN - nb0);          // nodes in this bucket
    int base = rs[nb0];
    int end = (nb0 + 256 < NN) ? rs[nb0 + 256] : EE;
    loc[t] = 0;
    if (t < nnb) off[t] = rs[nb0 + t] - base;
    __syncthreads();
    for (int e = base + t; e < end; e += 256) {
        int2 v = tmp8[e];
        int nl = v.y - nb0;
        int rank = atomicAdd(&loc[nl], 1);
        es[base + off[nl] + rank] = v.x;
    }
}

// -------- xf0: hb = embedding[x_atoms]; xf = hb @ conv1_w (fused, layer 0) ---
__global__ __launch_bounds__(256) void xf0_kernel(const int* __restrict__ x_atoms,
                                                  const float* __restrict__ emb,
                                                  const bf16* __restrict__ c1t,
                                                  bf16* __restrict__ hb,
                                                  bf16* __restrict__ xf) {
    __shared__ bf16 sB[128 * 136];
    int tid = threadIdx.x;
    for (int idx = tid * 8; idx < 128 * 128; idx += 2048) {
        int n = idx >> 7, k = idx & 127;
        *(bf16x8*)&sB[n * 136 + k] = *(const bf16x8*)(c1t + idx);
    }
    int w = tid >> 6, lane = tid & 63, ln = lane & 15, kg = lane >> 4;
    int rowt = blockIdx.x * 64 + w * 16;
    int nrow = rowt + ln;
    int arow = min(nrow, NN - 1);
    bool rowok = nrow < NN;
    int atom = x_atoms[arow];
    __syncthreads();
    f32x4 acc[8] = {};
#pragma unroll
    for (int k0 = 0; k0 < 128; k0 += 32) {
        const float* ep = emb + (size_t)atom * HH + k0 + kg * 8;
        f32x4 u0 = *(const f32x4*)ep;
        f32x4 u1 = *(const f32x4*)(ep + 4);
        bf16x8 a;
#pragma unroll
        for (int q = 0; q < 4; q++) { a[q] = (bf16)u0[q]; a[q + 4] = (bf16)u1[q]; }
        if (rowok) *(bf16x8*)(hb + (size_t)nrow * HH + k0 + kg * 8) = a;
#pragma unroll
        for (int t = 0; t < 8; t++) {
            bf16x8 b = *(const bf16x8*)&sB[(t * 16 + ln) * 136 + k0 + kg * 8];
            acc[t] = mfma16(a, b, acc[t]);
        }
    }
#pragma unroll
    for (int t = 0; t < 8; t++) {
        int colt = t * 16 + ln;
#pragma unroll
        for (int r = 0; r < 4; r++) {
            int orow = rowt + kg * 4 + r;
            if (orow < NN) xf[orow * FF + colt] = (bf16)acc[t][r];
        }
    }
}

// -------- edge kernel: CSR, one wave/node, nearest-knot, 4 edges/iter --------
__global__ __launch_bounds__(256) void edge_kernel(const int* __restrict__ es,
                                                   const int* __restrict__ rs,
                                                   const int* __restrict__ hist,
                                                   const bf16* __restrict__ xf,
                                                   const bf16* __restrict__ tab,
                                                   bf16* __restrict__ aggb) {
    int tid = threadIdx.x;
    int w = tid >> 6, lane = tid & 63;
    int q = lane >> 4, cl = lane & 15;      // quarter q handles edge 4j+q; lane covers ch [8cl,8cl+8)
    int n = blockIdx.x * 4 + w;
    int start = rs[n], deg = hist[n];
    float a0 = 0.f, a1 = 0.f, a2 = 0.f, a3 = 0.f;
    float a4 = 0.f, a5 = 0.f, a6 = 0.f, a7 = 0.f;
    for (int base = 0; base < deg; base += 64) {
        int cnt = min(deg - base, 64);
        int pv = (lane < cnt) ? es[start + base + lane] : 0;
        int iters = (cnt + 3) >> 2;
#pragma unroll 4
        for (int j = 0; j < iters; j++) {
            int jj = 4 * j + q;
            bool valid = jj < cnt;
            int v = __shfl(pv, jj);
            int k = v & 8191;
            int s = v >> 13;
            u32x4 tp = *(const u32x4*)(tab + (size_t)k * FF + 8 * cl);
            u32x4 xu = *(const u32x4*)(xf + (size_t)s * FF + 8 * cl);
            unsigned t0 = valid ? tp.x : 0u;
            unsigned t1 = valid ? tp.y : 0u;
            unsigned t2 = valid ? tp.z : 0u;
            unsigned t3 = valid ? tp.w : 0u;
            a0 = fmaf(blo(t0), blo(xu.x), a0);
            a1 = fmaf(bhi(t0), bhi(xu.x), a1);
            a2 = fmaf(blo(t1), blo(xu.y), a2);
            a3 = fmaf(bhi(t1), bhi(xu.y), a3);
            a4 = fmaf(blo(t2), blo(xu.z), a4);
            a5 = fmaf(bhi(t2), bhi(xu.z), a5);
            a6 = fmaf(blo(t3), blo(xu.w), a6);
            a7 = fmaf(bhi(t3), bhi(xu.w), a7);
        }
    }
    a0 += __shfl_xor(a0, 16); a0 += __shfl_xor(a0, 32);
    a1 += __shfl_xor(a1, 16); a1 += __shfl_xor(a1, 32);
    a2 += __shfl_xor(a2, 16); a2 += __shfl_xor(a2, 32);
    a3 += __shfl_xor(a3, 16); a3 += __shfl_xor(a3, 32);
    a4 += __shfl_xor(a4, 16); a4 += __shfl_xor(a4, 32);
    a5 += __shfl_xor(a5, 16); a5 += __shfl_xor(a5, 32);
    a6 += __shfl_xor(a6, 16); a6 += __shfl_xor(a6, 32);
    a7 += __shfl_xor(a7, 16); a7 += __shfl_xor(a7, 32);
    if (q == 0) {
        bf16x8 pk;
        pk[0] = (bf16)a0; pk[1] = (bf16)a1; pk[2] = (bf16)a2; pk[3] = (bf16)a3;
        pk[4] = (bf16)a4; pk[5] = (bf16)a5; pk[6] = (bf16)a6; pk[7] = (bf16)a7;
        *(bf16x8*)(aggb + (size_t)n * FF + 8 * cl) = pk;
    }
}

// -------- update: transposed-output GEMMs (thread = 1 node x 4-feat spans) ---
__global__ __launch_bounds__(256) void update_kernel(const bf16* __restrict__ aggb,
                                                     const bf16* __restrict__ c2t,
                                                     const float* __restrict__ c2b,
                                                     const bf16* __restrict__ ilt,
                                                     const float* __restrict__ ilb,
                                                     bf16* __restrict__ hb,
                                                     const bf16* __restrict__ c1n,
                                                     bf16* __restrict__ xf_out,
                                                     const bf16* __restrict__ l1t,
                                                     const float* __restrict__ l1b,
                                                     const bf16* __restrict__ l2t,
                                                     const float* __restrict__ l2b,
                                                     float* __restrict__ partial) {
    __shared__ bf16 sB[128 * 136];   // restaged per GEMM
    __shared__ bf16 sT[64 * 136];
    int tid = threadIdx.x;
    int w = tid >> 6, lane = tid & 63, ln = lane & 15, kg = lane >> 4;
    int rowt = blockIdx.x * 64 + w * 16;
    int nrow = rowt + ln;                 // this thread's node (transposed layout)
    int arow = min(nrow, NN - 1);
    bool rowok = nrow < NN;
    // prefetch residual h: node nrow, feats t*16+kg*4 .. +4
    bf16x4 hpre[8];
#pragma unroll
    for (int t = 0; t < 8; t++)
        hpre[t] = *(const bf16x4*)(hb + (size_t)arow * HH + t * 16 + kg * 4);
    for (int idx = tid * 8; idx < 128 * 128; idx += 2048) {
        int n = idx >> 7, k = idx & 127;
        *(bf16x8*)&sB[n * 136 + k] = *(const bf16x8*)(c2t + idx);
    }
    __syncthreads();
    // GEMM1 (Ct): out[feat][node] = conv2^T @ agg^T  (operand-swapped MFMA)
    f32x4 acc[8] = {};
#pragma unroll
    for (int k0 = 0; k0 < 128; k0 += 32) {
        bf16x8 bfrag = *(const bf16x8*)(aggb + (size_t)arow * FF + k0 + kg * 8);
#pragma unroll
        for (int t = 0; t < 8; t++) {
            bf16x8 afrag = *(const bf16x8*)&sB[(t * 16 + ln) * 136 + k0 + kg * 8];
            acc[t] = mfma16(afrag, bfrag, acc[t]);
        }
    }
    // epilogue1: thread holds feats t*16+kg*4+[0..4) of node nrow -> b64 LDS writes
#pragma unroll
    for (int t = 0; t < 8; t++) {
        f32x4 bb = *(const f32x4*)(c2b + t * 16 + kg * 4);
        bf16x4 pk;
#pragma unroll
        for (int r = 0; r < 4; r++) pk[r] = (bf16)sspf(acc[t][r] + bb[r]);
        *(bf16x4*)&sT[(w * 16 + ln) * 136 + t * 16 + kg * 4] = pk;
    }
    __syncthreads();
    for (int idx = tid * 8; idx < 128 * 128; idx += 2048) {
        int n = idx >> 7, k = idx & 127;
        *(bf16x8*)&sB[n * 136 + k] = *(const bf16x8*)(ilt + idx);
    }
    __syncthreads();
    f32x4 acc2[8] = {};
#pragma unroll
    for (int k0 = 0; k0 < 128; k0 += 32) {
        bf16x8 bfrag = *(const bf16x8*)&sT[(w * 16 + ln) * 136 + k0 + kg * 8];
#pragma unroll
        for (int t = 0; t < 8; t++) {
            bf16x8 afrag = *(const bf16x8*)&sB[(t * 16 + ln) * 136 + k0 + kg * 8];
            acc2[t] = mfma16(afrag, bfrag, acc2[t]);
        }
    }
    bool is_last = (c1n == nullptr);
    // epilogue2: residual add, vector stores (own sT rows only -> no barrier needed)
#pragma unroll
    for (int t = 0; t < 8; t++) {
        f32x4 bb = *(const f32x4*)(ilb + t * 16 + kg * 4);
        bf16x4 pk;
#pragma unroll
        for (int r = 0; r < 4; r++)
            pk[r] = (bf16)((float)hpre[t][r] + acc2[t][r] + bb[r]);
        if (rowok && !is_last) *(bf16x4*)(hb + (size_t)nrow * HH + t * 16 + kg * 4) = pk;
        *(bf16x4*)&sT[(w * 16 + ln) * 136 + t * 16 + kg * 4] = pk;
    }
    if (!is_last) {
        // fused next-layer xf = h_new @ conv1_next (same transposed form)
        __syncthreads();
        for (int idx = tid * 8; idx < 128 * 128; idx += 2048) {
            int n = idx >> 7, k = idx & 127;
            *(bf16x8*)&sB[n * 136 + k] = *(const bf16x8*)(c1n + idx);
        }
        __syncthreads();
        f32x4 acc3[8] = {};
#pragma unroll
        for (int k0 = 0; k0 < 128; k0 += 32) {
            bf16x8 bfrag = *(const bf16x8*)&sT[(w * 16 + ln) * 136 + k0 + kg * 8];
#pragma unroll
            for (int t = 0; t < 8; t++) {
                bf16x8 afrag = *(const bf16x8*)&sB[(t * 16 + ln) * 136 + k0 + kg * 8];
                acc3[t] = mfma16(afrag, bfrag, acc3[t]);
            }
        }
#pragma unroll
        for (int t = 0; t < 8; t++) {
            bf16x4 pk;
#pragma unroll
            for (int r = 0; r < 4; r++) pk[r] = (bf16)acc3[t][r];
            if (rowok) *(bf16x4*)(xf_out + (size_t)nrow * FF + t * 16 + kg * 4) = pk;
        }
    } else {
        // fused head: ssp(h@lin1+b)@lin2+b, per-block partial sum (runs once)
        __syncthreads();
        for (int idx = tid * 8; idx < 64 * 128; idx += 2048) {
            int n = idx >> 7, k = idx & 127;
            *(bf16x8*)&sB[n * 136 + k] = *(const bf16x8*)(l1t + idx);
        }
        __syncthreads();
        f32x4 acch[4] = {};
#pragma unroll
        for (int k0 = 0; k0 < 128; k0 += 32) {
            bf16x8 a = *(const bf16x8*)&sT[(w * 16 + ln) * 136 + k0 + kg * 8];
#pragma unroll
            for (int t = 0; t < 4; t++) {
                bf16x8 b = *(const bf16x8*)&sB[(t * 16 + ln) * 136 + k0 + kg * 8];
                acch[t] = mfma16(a, b, acch[t]);
            }
        }
#pragma unroll
        for (int t = 0; t < 4; t++) {
            int colt = t * 16 + ln;
            float bb = l1b[colt];
#pragma unroll
            for (int r = 0; r < 4; r++)
                sT[(w * 16 + kg * 4 + r) * 136 + colt] = (bf16)sspf(acch[t][r] + bb);
        }
        __syncthreads();
        for (int idx = tid * 8; idx < 64 * 64; idx += 2048) {
            int n = idx >> 6, k = idx & 63;
            *(bf16x8*)&sB[n * 136 + k] = *(const bf16x8*)(l2t + idx);
        }
        __syncthreads();
        f32x4 acc2h[4] = {};
#pragma unroll
        for (int k0 = 0; k0 < 64; k0 += 32) {
            bf16x8 a = *(const bf16x8*)&sT[(w * 16 + ln) * 136 + k0 + kg * 8];
#pragma unroll
            for (int t = 0; t < 4; t++) {
                bf16x8 b = *(const bf16x8*)&sB[(t * 16 + ln) * 136 + k0 + kg * 8];
                acc2h[t] = mfma16(a, b, acc2h[t]);
            }
        }
        __syncthreads();   // all sT reads done; reuse as f32 scratch
        float* sPart = (float*)sT;
#pragma unroll
        for (int t = 0; t < 4; t++) {
            int colt = t * 16 + ln;
            float bb = l2b[colt];
            float v = 0.f;
#pragma unroll
            for (int r = 0; r < 4; r++) {
                int orow = rowt + kg * 4 + r;
                if (orow < NN) v += acc2h[t][r] + bb;
            }
            v += __shfl_xor(v, 16);
            v += __shfl_xor(v, 32);
            if (kg == 0) sPart[w * 64 + colt] = v;
        }
        __syncthreads();
        if (tid < 64) {
            float s = sPart[tid] + sPart[64 + tid] + sPart[128 + tid] + sPart[192 + tid];
            partial[blockIdx.x * 64 + tid] = s;
        }
    }
}

// -------- finalA: one block per column, parallel reduce over 782 partials ----
__global__ __launch_bounds__(256) void finalA_kernel(const float* __restrict__ partial,
                                                     float* __restrict__ colsum) {
    __shared__ float red[256];
    int c = blockIdx.x, t = threadIdx.x;
    float s = 0.f;
    for (int b = t; b < NBLK; b += 256) s += partial[b * 64 + c];
    red[t] = s;
    __syncthreads();
    for (int off = 128; off > 0; off >>= 1) {
        if (t < off) red[t] += red[t + off];
        __syncthreads();
    }
    if (t == 0) colsum[c] = red[0];
}

// -------- finalB: readout GEMV (64x12, trivial) ------------------------------
__global__ __launch_bounds__(64) void finalB_kernel(const float* __restrict__ colsum,
                                                    const float* __restrict__ rw,
                                                    const float* __restrict__ rb,
                                                    float* __restrict__ out) {
    __shared__ float sv[64];
    int j = threadIdx.x;
    sv[j] = colsum[j];
    __syncthreads();
    if (j < OUT_DIM) {
        float o = rb[j];
        for (int i = 0; i < H2D; i++) o += sv[i] * rw[i * OUT_DIM + j];
        out[j] = o;
    }
}

// -------- launch -------------------------------------------------------------
extern "C" void kernel_launch(void* const* d_in, const int* in_sizes, int n_in,
                              void* d_out, int out_size, void* d_ws, size_t ws_size,
                              hipStream_t stream) {
    const int*   x_atoms    = (const int*)d_in[0];
    const int*   edge_index = (const int*)d_in[1];
    const float* edge_attr  = (const float*)d_in[2];
    const float* embedding  = (const float*)d_in[3];
    const float* mlp_w1     = (const float*)d_in[4];
    const float* mlp_b1     = (const float*)d_in[5];
    const float* mlp_w2     = (const float*)d_in[6];
    const float* mlp_b2     = (const float*)d_in[7];
    const float* conv1_w    = (const float*)d_in[8];
    const float* conv2_w    = (const float*)d_in[9];
    const float* conv2_b    = (const float*)d_in[10];
    const float* int_lin_w  = (const float*)d_in[11];
    const float* int_lin_b  = (const float*)d_in[12];
    const float* lin1_w     = (const float*)d_in[13];
    const float* lin1_b     = (const float*)d_in[14];
    const float* lin2_w     = (const float*)d_in[15];
    const float* lin2_b     = (const float*)d_in[16];
    const float* readout_w  = (const float*)d_in[17];
    const float* readout_b  = (const float*)d_in[18];

    char* ws = (char*)d_ws;
    bf16*  hb      = (bf16*)(ws + 0);              // 12,800,000
    bf16*  xfA     = (bf16*)(ws + 12800000);       // 12,800,000
    bf16*  xfB     = (bf16*)(ws + 25600000);       // 12,800,000
    bf16*  aggb    = (bf16*)(ws + 38400000);       // 12,800,000
    float* partial = (float*)(ws + 51200000);      // 200,192
    size_t wb = 51400192;
    bf16* c1t = (bf16*)(ws + wb);                  // 196,608
    bf16* c2t = (bf16*)(ws + wb + 196608);
    bf16* ilt = (bf16*)(ws + wb + 393216);
    bf16* w1t = (bf16*)(ws + wb + 589824);         // 98,304
    bf16* w2t = (bf16*)(ws + wb + 688128);         // 196,608
    bf16* l1t = (bf16*)(ws + wb + 884736);         // 16,384
    bf16* l2t = (bf16*)(ws + wb + 901120);         // 8,192 -> ends 52,309,504
    int*   d_hist = (int*)(ws + 52309504);         // 200,000
    int*   d_rs   = (int*)(ws + 52509504);         // 200,000
    int*   d_bcur = (int*)(ws + 52709504);         // 1,024 (bucket_cur)
    int*   d_bsum = (int*)(ws + 52710528);         // 1,024
    int*   d_es   = (int*)(ws + 52711552);         // 3,200,000 -> 55,911,552
    bf16*  tab    = (bf16*)(ws + 55911552);        // 6*4097*128*2 = 6,292,992 -> 62,204,544
    int2*  d_tmp8 = (int2*)(ws + 62204544);        // 6,400,000 -> 68,604,544
    float* colsum = (float*)(ws + 68604544);       // 256 -> 68,604,800

    PrepArgs pa = { conv1_w, conv2_w, int_lin_w, mlp_w1, mlp_w2, lin1_w, lin2_w,
                    c1t, c2t, ilt, w1t, w2t, l1t, l2t, d_hist };
    prep_kernel<<<32, 256, 0, stream>>>(pa);
    table_kernel<<<LL * 65, 256, 0, stream>>>(w1t, w2t, mlp_b1, mlp_b2, tab);

    // sort edges by dst (once; graph static across layers)
    hist_kernel<<<(EE + 255) / 256, 256, 0, stream>>>(edge_index, d_hist);
    scanA_kernel<<<SB, 256, 0, stream>>>(d_hist, d_bsum);
    scanB_kernel<<<1, 256, 0, stream>>>(d_bsum);
    scanC_kernel<<<SB, 256, 0, stream>>>(d_hist, d_bsum, d_rs, d_bcur);
    scat1_kernel<<<NBUK, 256, 0, stream>>>(edge_attr, edge_index, d_bcur, d_tmp8);
    scat2_kernel<<<NBUK, 256, 0, stream>>>(d_rs, d_tmp8, d_es);

    xf0_kernel<<<NBLK, 256, 0, stream>>>(x_atoms, embedding, c1t, hb, xfA);
    bf16* xf_in = xfA;
    bf16* xf_out = xfB;
    for (int l = 0; l < LL; l++) {
        edge_kernel<<<NN / 4, 256, 0, stream>>>(d_es, d_rs, d_hist, xf_in,
                                                tab + (size_t)l * (NK + 1) * FF, aggb);
        const bf16* c1n = (l + 1 < LL) ? (c1t + (size_t)(l + 1) * FF * HH) : nullptr;
        update_kernel<<<NBLK, 256, 0, stream>>>(aggb, c2t + (size_t)l * HH * FF,
                                                conv2_b + l * HH,
                                                ilt + (size_t)l * HH * HH, int_lin_b + l * HH,
                                                hb, c1n, xf_out,
                                                l1t, lin1_b, l2t, lin2_b, partial);
        bf16* tmp = xf_in; xf_in = xf_out; xf_out = tmp;
    }
    finalA_kernel<<<64, 256, 0, stream>>>(partial, colsum);
    finalB_kernel<<<1, 64, 0, stream>>>(colsum, readout_w, readout_b, (float*)d_out);
}